// Round 1
// baseline (1128.307 us; speedup 1.0000x reference)
//
#include <hip/hip_runtime.h>
#include <math.h>

#define N_NODES 20000
#define N_EDGES 640000
#define DD 128
#define RR 32
#define HH 128
#define PI_F 3.14159265358979323846f

__device__ __forceinline__ float silu_f(float x) { return x / (1.0f + __expf(-x)); }
__device__ __forceinline__ float sigmoid_f(float x) { return 1.0f / (1.0f + __expf(-x)); }

// ---------------- LayerNorm: one wave per row ----------------
__global__ __launch_bounds__(256) void ln_kernel(const float* __restrict__ x,
                                                 const float* __restrict__ g,
                                                 const float* __restrict__ b,
                                                 float* __restrict__ xn) {
    int wid = (blockIdx.x * 256 + threadIdx.x) >> 6;   // global wave id = row
    int lane = threadIdx.x & 63;
    if (wid >= N_NODES) return;
    const float* row = x + (size_t)wid * DD;
    float v0 = row[lane], v1 = row[lane + 64];
    float s = v0 + v1, sq = v0 * v0 + v1 * v1;
    #pragma unroll
    for (int o = 32; o > 0; o >>= 1) { s += __shfl_xor(s, o); sq += __shfl_xor(sq, o); }
    float mu = s * (1.0f / 128.0f);
    float var = sq * (1.0f / 128.0f) - mu * mu;
    float inv = rsqrtf(var + 1e-5f);
    float* orow = xn + (size_t)wid * DD;
    orow[lane]      = (v0 - mu) * inv * g[lane]      + b[lane];
    orow[lane + 64] = (v1 - mu) * inv * g[lane + 64] + b[lane + 64];
}

// ---------------- Edge pipeline: 64 edges per block, 256 threads ----------------
// Mapping A (MLP layers): e = tid&63 (per-lane), fg = tid>>6 (wave-uniform feature group
// of 32) -> weight loads are scalar (s_load), LDS h reads are per-lane conflict-free
// (row stride 129 words => bank (e+k)%32).
// Mapping B (scatter): f = tid&127, eg = tid>>7 -> coalesced gather/atomic rows.
__global__ __launch_bounds__(256) void edge_kernel(
    const float* __restrict__ xn,
    const int* __restrict__ esrc, const int* __restrict__ edst,
    const float* __restrict__ rbf, const float* __restrict__ elen,
    const float* __restrict__ wm_w1, const float* __restrict__ wm_b1,
    const float* __restrict__ wm_w2, const float* __restrict__ wm_b2,
    const float* __restrict__ wm_w3, const float* __restrict__ wm_b3,
    const float* __restrict__ eg_w1, const float* __restrict__ eg_b1,
    const float* __restrict__ eg_w2, const float* __restrict__ eg_b2,
    float* __restrict__ agg, float* __restrict__ nrm)
{
    __shared__ float rbf_s[64 * 33];
    __shared__ float bufA[64 * 129];
    __shared__ float bufB[64 * 129];
    __shared__ float ew_s[64];
    __shared__ float pd_s[4][64];
    __shared__ int   src_s[64], dst_s[64];

    const int tid = threadIdx.x;
    const int eb = blockIdx.x * 64;

    // cooperative rbf tile load (64x32) into padded LDS
    #pragma unroll
    for (int i = 0; i < 8; ++i) {
        int idx = tid + i * 256;
        float v = rbf[(size_t)eb * RR + idx];
        rbf_s[(idx >> 5) * 33 + (idx & 31)] = v;
    }
    if (tid < 64) {
        int e = eb + tid;
        src_s[tid] = esrc[e];
        dst_s[tid] = edst[e];
        float len = elen[e];
        float cut = (len <= 5.0f) ? 0.5f * (__cosf(PI_F * len * 0.2f) + 1.0f) : 0.0f;
        ew_s[tid] = cut;                      // holds cut for now
    }
    __syncthreads();

    const int e  = tid & 63;
    const int fg = __builtin_amdgcn_readfirstlane(tid >> 6);
    const int F0 = fg * 32;

    // ---- gate branch: g = silu(rbf @ eg_w1 + b); partial dot with eg_w2
    {
        float acc[32];
        #pragma unroll
        for (int j = 0; j < 32; ++j) acc[j] = eg_b1[F0 + j];
        for (int k = 0; k < RR; ++k) {
            float hv = rbf_s[e * 33 + k];
            const float* wk = eg_w1 + k * HH + F0;
            #pragma unroll
            for (int j = 0; j < 32; ++j) acc[j] = fmaf(hv, wk[j], acc[j]);
        }
        float pd = 0.0f;
        #pragma unroll
        for (int j = 0; j < 32; ++j) pd += silu_f(acc[j]) * eg_w2[F0 + j];
        pd_s[fg][e] = pd;
    }
    __syncthreads();
    if (tid < 64) {
        float dot = pd_s[0][tid] + pd_s[1][tid] + pd_s[2][tid] + pd_s[3][tid] + eg_b2[0];
        float ew = ew_s[tid] * sigmoid_f(dot);
        ew_s[tid] = ew;                       // edge weight (read after later barriers)
        atomicAdd(&nrm[dst_s[tid]], ew);
    }

    // ---- layer 1: bufA = silu(rbf @ wm_w1 + b1)
    {
        float acc[32];
        #pragma unroll
        for (int j = 0; j < 32; ++j) acc[j] = wm_b1[F0 + j];
        for (int k = 0; k < RR; ++k) {
            float hv = rbf_s[e * 33 + k];
            const float* wk = wm_w1 + k * HH + F0;
            #pragma unroll
            for (int j = 0; j < 32; ++j) acc[j] = fmaf(hv, wk[j], acc[j]);
        }
        #pragma unroll
        for (int j = 0; j < 32; ++j) bufA[e * 129 + F0 + j] = silu_f(acc[j]);
    }
    __syncthreads();

    // ---- layer 2: bufB = silu(bufA @ wm_w2 + b2)
    {
        float acc[32];
        #pragma unroll
        for (int j = 0; j < 32; ++j) acc[j] = wm_b2[F0 + j];
        for (int k = 0; k < HH; ++k) {
            float hv = bufA[e * 129 + k];
            const float* wk = wm_w2 + k * HH + F0;
            #pragma unroll
            for (int j = 0; j < 32; ++j) acc[j] = fmaf(hv, wk[j], acc[j]);
        }
        #pragma unroll
        for (int j = 0; j < 32; ++j) bufB[e * 129 + F0 + j] = silu_f(acc[j]);
    }
    __syncthreads();

    // ---- layer 3: bufA = bufB @ wm_w3 + b3   (w_rad)
    {
        float acc[32];
        #pragma unroll
        for (int j = 0; j < 32; ++j) acc[j] = wm_b3[F0 + j];
        for (int k = 0; k < HH; ++k) {
            float hv = bufB[e * 129 + k];
            const float* wk = wm_w3 + k * DD + F0;
            #pragma unroll
            for (int j = 0; j < 32; ++j) acc[j] = fmaf(hv, wk[j], acc[j]);
        }
        #pragma unroll
        for (int j = 0; j < 32; ++j) bufA[e * 129 + F0 + j] = acc[j];
    }
    __syncthreads();

    // ---- gather x_norm[src], gate, scatter-add (mapping B, coalesced)
    {
        const int f = tid & 127;
        const int eg = tid >> 7;
        #pragma unroll 4
        for (int i = 0; i < 32; ++i) {
            int le = eg * 32 + i;
            float m = xn[(size_t)src_s[le] * DD + f] * bufA[le * 129 + f] * ew_s[le];
            atomicAdd(&agg[(size_t)dst_s[le] * DD + f], m);
        }
    }
}

// ---------------- Node finalize: 64 nodes per block ----------------
__global__ __launch_bounds__(256) void node_kernel(
    const float* __restrict__ x, const float* __restrict__ xn,
    const float* __restrict__ agg, const float* __restrict__ nrm,
    const float* __restrict__ mm_w1, const float* __restrict__ mm_b1,
    const float* __restrict__ mm_w2, const float* __restrict__ mm_b2,
    const float* __restrict__ sl_w, const float* __restrict__ sl_b,
    const float* __restrict__ ul_w, const float* __restrict__ ul_b,
    const float* __restrict__ res_scale, float* __restrict__ out)
{
    __shared__ float bufA[64 * 129];
    __shared__ float bufB[64 * 129];
    __shared__ float rs_s[64];

    const int tid = threadIdx.x;
    const int nb = blockIdx.x * 64;

    if (tid < 64) {
        int n = nb + tid;
        rs_s[tid] = (n < N_NODES) ? 1.0f / fmaxf(nrm[n], 1e-8f) : 0.0f;
    }
    __syncthreads();

    // P2 [B]: bufA = agg / norm
    {
        const int f = tid & 127, ng = tid >> 7;
        for (int i = 0; i < 32; ++i) {
            int ln = ng * 32 + i, n = nb + ln;
            bufA[ln * 129 + f] = (n < N_NODES) ? agg[(size_t)n * DD + f] * rs_s[ln] : 0.0f;
        }
    }
    __syncthreads();

    const int e  = tid & 63;
    const int fg = __builtin_amdgcn_readfirstlane(tid >> 6);
    const int F0 = fg * 32;

    // P3: bufB = silu(bufA @ mm_w1 + b1)
    {
        float acc[32];
        #pragma unroll
        for (int j = 0; j < 32; ++j) acc[j] = mm_b1[F0 + j];
        for (int k = 0; k < DD; ++k) {
            float hv = bufA[e * 129 + k];
            const float* wk = mm_w1 + k * HH + F0;
            #pragma unroll
            for (int j = 0; j < 32; ++j) acc[j] = fmaf(hv, wk[j], acc[j]);
        }
        #pragma unroll
        for (int j = 0; j < 32; ++j) bufB[e * 129 + F0 + j] = silu_f(acc[j]);
    }
    __syncthreads();

    // P4: bufA = bufB @ mm_w2 + b2   (agg2)
    {
        float acc[32];
        #pragma unroll
        for (int j = 0; j < 32; ++j) acc[j] = mm_b2[F0 + j];
        for (int k = 0; k < HH; ++k) {
            float hv = bufB[e * 129 + k];
            const float* wk = mm_w2 + k * DD + F0;
            #pragma unroll
            for (int j = 0; j < 32; ++j) acc[j] = fmaf(hv, wk[j], acc[j]);
        }
        #pragma unroll
        for (int j = 0; j < 32; ++j) bufA[e * 129 + F0 + j] = acc[j];
    }
    __syncthreads();

    // P5 [B]: bufB = xn tile
    {
        const int f = tid & 127, ng = tid >> 7;
        for (int i = 0; i < 32; ++i) {
            int ln = ng * 32 + i, n = nb + ln;
            bufB[ln * 129 + f] = (n < N_NODES) ? xn[(size_t)n * DD + f] : 0.0f;
        }
    }
    __syncthreads();

    // P6: out = xn @ sl_w + agg2 @ ul_w + biases (regs), then stage to bufA
    {
        float acc[32];
        #pragma unroll
        for (int j = 0; j < 32; ++j) acc[j] = sl_b[F0 + j] + ul_b[F0 + j];
        for (int k = 0; k < DD; ++k) {
            float a = bufB[e * 129 + k];
            float c = bufA[e * 129 + k];
            const float* wk1 = sl_w + k * DD + F0;
            const float* wk2 = ul_w + k * DD + F0;
            #pragma unroll
            for (int j = 0; j < 32; ++j) acc[j] = fmaf(a, wk1[j], acc[j]);
            #pragma unroll
            for (int j = 0; j < 32; ++j) acc[j] = fmaf(c, wk2[j], acc[j]);
        }
        __syncthreads();
        #pragma unroll
        for (int j = 0; j < 32; ++j) bufA[e * 129 + F0 + j] = acc[j];
    }
    __syncthreads();

    // P7 [B]: final residual, coalesced store
    {
        float rs = res_scale[0];
        const int f = tid & 127, ng = tid >> 7;
        for (int i = 0; i < 32; ++i) {
            int ln = ng * 32 + i, n = nb + ln;
            if (n < N_NODES)
                out[(size_t)n * DD + f] = x[(size_t)n * DD + f] + rs * bufA[ln * 129 + f];
        }
    }
}

extern "C" void kernel_launch(void* const* d_in, const int* in_sizes, int n_in,
                              void* d_out, int out_size, void* d_ws, size_t ws_size,
                              hipStream_t stream) {
    const float* x     = (const float*)d_in[0];
    const int*   esrc  = (const int*)d_in[1];
    const int*   edst  = (const int*)d_in[2];
    // d_in[3] = edge_sh (unused by reference)
    const float* rbf   = (const float*)d_in[4];
    const float* elen  = (const float*)d_in[5];
    const float* ln_g  = (const float*)d_in[6];
    const float* ln_b  = (const float*)d_in[7];
    const float* wm_w1 = (const float*)d_in[8];
    const float* wm_b1 = (const float*)d_in[9];
    const float* wm_w2 = (const float*)d_in[10];
    const float* wm_b2 = (const float*)d_in[11];
    const float* wm_w3 = (const float*)d_in[12];
    const float* wm_b3 = (const float*)d_in[13];
    const float* eg_w1 = (const float*)d_in[14];
    const float* eg_b1 = (const float*)d_in[15];
    const float* eg_w2 = (const float*)d_in[16];
    const float* eg_b2 = (const float*)d_in[17];
    const float* mm_w1 = (const float*)d_in[18];
    const float* mm_b1 = (const float*)d_in[19];
    const float* mm_w2 = (const float*)d_in[20];
    const float* mm_b2 = (const float*)d_in[21];
    const float* sl_w  = (const float*)d_in[22];
    const float* sl_b  = (const float*)d_in[23];
    const float* ul_w  = (const float*)d_in[24];
    const float* ul_b  = (const float*)d_in[25];
    const float* rscl  = (const float*)d_in[26];

    float* xn  = (float*)d_ws;
    float* agg = xn + (size_t)N_NODES * DD;
    float* nrm = agg + (size_t)N_NODES * DD;

    hipMemsetAsync(agg, 0, (size_t)(N_NODES * DD + N_NODES) * sizeof(float), stream);
    ln_kernel<<<(N_NODES + 3) / 4, 256, 0, stream>>>(x, ln_g, ln_b, xn);
    edge_kernel<<<N_EDGES / 64, 256, 0, stream>>>(xn, esrc, edst, rbf, elen,
        wm_w1, wm_b1, wm_w2, wm_b2, wm_w3, wm_b3,
        eg_w1, eg_b1, eg_w2, eg_b2, agg, nrm);
    node_kernel<<<(N_NODES + 63) / 64, 256, 0, stream>>>(x, xn, agg, nrm,
        mm_w1, mm_b1, mm_w2, mm_b2, sl_w, sl_b, ul_w, ul_b, rscl, (float*)d_out);
}

// Round 2
// 837.712 us; speedup vs baseline: 1.3469x; 1.3469x over previous
//
#include <hip/hip_runtime.h>
#include <math.h>

#define N_NODES 20000
#define N_EDGES 640000
#define DD 128
#define RR 32
#define HH 128
#define PI_F 3.14159265358979323846f

typedef short bf16x8 __attribute__((ext_vector_type(8)));
typedef float f32x4 __attribute__((ext_vector_type(4)));

__device__ __forceinline__ float silu_f(float x) { return x / (1.0f + __expf(-x)); }
__device__ __forceinline__ float sigmoid_f(float x) { return 1.0f / (1.0f + __expf(-x)); }
__device__ __forceinline__ unsigned short f2bf(float x) {
    unsigned u = __float_as_uint(x);
    return (unsigned short)((u + 0x7FFFu + ((u >> 16) & 1u)) >> 16);
}

// ---------------- weight pack: W[K][F] fp32 -> bf16 MFMA-A-fragment order ----
// packed[((s*NT + t)*64 + l)*8 + j] = W[s*32 + (l>>4)*8 + j][t*16 + (l&15)]
__global__ __launch_bounds__(256) void pack_w_kernel(const float* __restrict__ src,
                                                     unsigned short* __restrict__ dst,
                                                     int K, int F) {
    int o = blockIdx.x * 256 + threadIdx.x;
    if (o >= K * F) return;
    int NT = F >> 4;
    int j = o & 7;
    int l = (o >> 3) & 63;
    int rest = o >> 9;
    int t = rest % NT;
    int s = rest / NT;
    int k = s * 32 + ((l >> 4) << 3) + j;
    int f = t * 16 + (l & 15);
    dst[o] = f2bf(src[(size_t)k * F + f]);
}

// ---------------- LayerNorm: one wave per row ----------------
__global__ __launch_bounds__(256) void ln_kernel(const float* __restrict__ x,
                                                 const float* __restrict__ g,
                                                 const float* __restrict__ b,
                                                 float* __restrict__ xn) {
    int wid = (blockIdx.x * 256 + threadIdx.x) >> 6;
    int lane = threadIdx.x & 63;
    if (wid >= N_NODES) return;
    const float* row = x + (size_t)wid * DD;
    float v0 = row[lane], v1 = row[lane + 64];
    float s = v0 + v1, sq = v0 * v0 + v1 * v1;
    #pragma unroll
    for (int o = 32; o > 0; o >>= 1) { s += __shfl_xor(s, o); sq += __shfl_xor(sq, o); }
    float mu = s * (1.0f / 128.0f);
    float var = sq * (1.0f / 128.0f) - mu * mu;
    float inv = rsqrtf(var + 1e-5f);
    float* orow = xn + (size_t)wid * DD;
    orow[lane]      = (v0 - mu) * inv * g[lane]      + b[lane];
    orow[lane + 64] = (v1 - mu) * inv * g[lane + 64] + b[lane + 64];
}

// ---------------- Edge pipeline (MFMA): 64 edges/block, 4 waves, 16 edges/wave
// Swapped layout: D[f][e] = A(Wt)[f][k] * B(act)[k][e].
// D frag: lane holds f = t*16 + (lane>>4)*4 + r  for edge e = lane&15.
// B frag: lane reads act[e = lane&15][k = (lane>>4)*8 + j] -> contiguous 16B.
// Waves are fully independent: no __syncthreads in this kernel.
__global__ __launch_bounds__(256) void edge_kernel(
    const float* __restrict__ xn,
    const int* __restrict__ esrc, const int* __restrict__ edst,
    const float* __restrict__ rbf, const float* __restrict__ elen,
    const unsigned short* __restrict__ wp_eg1, const unsigned short* __restrict__ wp_w1,
    const unsigned short* __restrict__ wp_w2,  const unsigned short* __restrict__ wp_w3,
    const float* __restrict__ eg_b1, const float* __restrict__ eg_w2,
    const float* __restrict__ eg_b2,
    const float* __restrict__ wm_b1, const float* __restrict__ wm_b2,
    const float* __restrict__ wm_b3,
    float* __restrict__ agg, float* __restrict__ nrm)
{
    // per-wave ping-pong activation buffers, row pitch 136 bf16 (272B) to
    // spread the 16-row b128 reads across banks (2-way max = free)
    __shared__ unsigned short act[4][2][16 * 136];

    const int tid  = threadIdx.x;
    const int w    = tid >> 6;
    const int lane = tid & 63;
    const int er   = lane & 15;   // edge row within wave (= D col)
    const int kq   = lane >> 4;   // quarter index
    const int e    = blockIdx.x * 64 + w * 16 + er;

    // B-frag of rbf: 8 consecutive k, fp32 -> bf16
    const float4* rp = (const float4*)(rbf + (size_t)e * RR + kq * 8);
    float4 r0 = rp[0], r1 = rp[1];
    bf16x8 bfr;
    bfr[0] = (short)f2bf(r0.x); bfr[1] = (short)f2bf(r0.y);
    bfr[2] = (short)f2bf(r0.z); bfr[3] = (short)f2bf(r0.w);
    bfr[4] = (short)f2bf(r1.x); bfr[5] = (short)f2bf(r1.y);
    bfr[6] = (short)f2bf(r1.z); bfr[7] = (short)f2bf(r1.w);

    const int src = esrc[e];
    const int dst = edst[e];
    const float len = elen[e];
    const float cut = (len <= 5.0f) ? 0.5f * (__cosf(PI_F * len * 0.2f) + 1.0f) : 0.0f;

    // ---- gate branch: silu(rbf@eg_w1+b1) . eg_w2, all in-register ----
    float pdot = 0.0f;
    #pragma unroll
    for (int t = 0; t < 8; ++t) {
        bf16x8 af = *(const bf16x8*)(wp_eg1 + ((size_t)t * 64 + lane) * 8);
        f32x4 z = {0.f, 0.f, 0.f, 0.f};
        f32x4 c = __builtin_amdgcn_mfma_f32_16x16x32_bf16(af, bfr, z, 0, 0, 0);
        float4 b1 = *(const float4*)(eg_b1 + t * 16 + kq * 4);
        float4 w2 = *(const float4*)(eg_w2 + t * 16 + kq * 4);
        pdot += silu_f(c[0] + b1.x) * w2.x + silu_f(c[1] + b1.y) * w2.y
              + silu_f(c[2] + b1.z) * w2.z + silu_f(c[3] + b1.w) * w2.w;
    }
    pdot += __shfl_xor(pdot, 16);
    pdot += __shfl_xor(pdot, 32);
    const float ew = cut * sigmoid_f(pdot + eg_b2[0]);
    if (lane < 16 && ew != 0.0f) atomicAdd(&nrm[dst], ew);

    unsigned short* buf0 = &act[w][0][0];
    unsigned short* buf1 = &act[w][1][0];

    // ---- L1: buf0 = silu(rbf @ wm_w1 + b1) ----
    #pragma unroll
    for (int t = 0; t < 8; ++t) {
        bf16x8 af = *(const bf16x8*)(wp_w1 + ((size_t)t * 64 + lane) * 8);
        f32x4 z = {0.f, 0.f, 0.f, 0.f};
        f32x4 c = __builtin_amdgcn_mfma_f32_16x16x32_bf16(af, bfr, z, 0, 0, 0);
        float4 b1 = *(const float4*)(wm_b1 + t * 16 + kq * 4);
        unsigned h01 = (unsigned)f2bf(silu_f(c[0] + b1.x)) | ((unsigned)f2bf(silu_f(c[1] + b1.y)) << 16);
        unsigned h23 = (unsigned)f2bf(silu_f(c[2] + b1.z)) | ((unsigned)f2bf(silu_f(c[3] + b1.w)) << 16);
        *(uint2*)(buf0 + er * 136 + t * 16 + kq * 4) = make_uint2(h01, h23);
    }

    // ---- L2: buf1 = silu(buf0 @ wm_w2 + b2) ----
    bf16x8 bf[4];
    #pragma unroll
    for (int s = 0; s < 4; ++s)
        bf[s] = *(const bf16x8*)(buf0 + er * 136 + s * 32 + kq * 8);
    #pragma unroll
    for (int t = 0; t < 8; ++t) {
        f32x4 c = {0.f, 0.f, 0.f, 0.f};
        #pragma unroll
        for (int s = 0; s < 4; ++s) {
            bf16x8 af = *(const bf16x8*)(wp_w2 + (((size_t)s * 8 + t) * 64 + lane) * 8);
            c = __builtin_amdgcn_mfma_f32_16x16x32_bf16(af, bf[s], c, 0, 0, 0);
        }
        float4 b2 = *(const float4*)(wm_b2 + t * 16 + kq * 4);
        unsigned h01 = (unsigned)f2bf(silu_f(c[0] + b2.x)) | ((unsigned)f2bf(silu_f(c[1] + b2.y)) << 16);
        unsigned h23 = (unsigned)f2bf(silu_f(c[2] + b2.z)) | ((unsigned)f2bf(silu_f(c[3] + b2.w)) << 16);
        *(uint2*)(buf1 + er * 136 + t * 16 + kq * 4) = make_uint2(h01, h23);
    }

    // ---- L3 + gather/gate/scatter fused per tile ----
    #pragma unroll
    for (int s = 0; s < 4; ++s)
        bf[s] = *(const bf16x8*)(buf1 + er * 136 + s * 32 + kq * 8);

    const float* xrow = xn + (size_t)src * DD;
    float* arow = agg + (size_t)dst * DD;
    const bool live = (ew != 0.0f);

    #pragma unroll
    for (int t = 0; t < 8; ++t) {
        f32x4 c = {0.f, 0.f, 0.f, 0.f};
        #pragma unroll
        for (int s = 0; s < 4; ++s) {
            bf16x8 af = *(const bf16x8*)(wp_w3 + (((size_t)s * 8 + t) * 64 + lane) * 8);
            c = __builtin_amdgcn_mfma_f32_16x16x32_bf16(af, bf[s], c, 0, 0, 0);
        }
        if (live) {
            float4 b3 = *(const float4*)(wm_b3 + t * 16 + kq * 4);
            float4 xv = *(const float4*)(xrow + t * 16 + kq * 4);
            const int f = t * 16 + kq * 4;
            atomicAdd(&arow[f + 0], (c[0] + b3.x) * xv.x * ew);
            atomicAdd(&arow[f + 1], (c[1] + b3.y) * xv.y * ew);
            atomicAdd(&arow[f + 2], (c[2] + b3.z) * xv.z * ew);
            atomicAdd(&arow[f + 3], (c[3] + b3.w) * xv.w * ew);
        }
    }
}

// ---------------- Node finalize: 64 nodes per block (unchanged fp32) -------
__global__ __launch_bounds__(256) void node_kernel(
    const float* __restrict__ x, const float* __restrict__ xn,
    const float* __restrict__ agg, const float* __restrict__ nrm,
    const float* __restrict__ mm_w1, const float* __restrict__ mm_b1,
    const float* __restrict__ mm_w2, const float* __restrict__ mm_b2,
    const float* __restrict__ sl_w, const float* __restrict__ sl_b,
    const float* __restrict__ ul_w, const float* __restrict__ ul_b,
    const float* __restrict__ res_scale, float* __restrict__ out)
{
    __shared__ float bufA[64 * 129];
    __shared__ float bufB[64 * 129];
    __shared__ float rs_s[64];

    const int tid = threadIdx.x;
    const int nb = blockIdx.x * 64;

    if (tid < 64) {
        int n = nb + tid;
        rs_s[tid] = (n < N_NODES) ? 1.0f / fmaxf(nrm[n], 1e-8f) : 0.0f;
    }
    __syncthreads();

    {
        const int f = tid & 127, ng = tid >> 7;
        for (int i = 0; i < 32; ++i) {
            int ln = ng * 32 + i, n = nb + ln;
            bufA[ln * 129 + f] = (n < N_NODES) ? agg[(size_t)n * DD + f] * rs_s[ln] : 0.0f;
        }
    }
    __syncthreads();

    const int e  = tid & 63;
    const int fg = __builtin_amdgcn_readfirstlane(tid >> 6);
    const int F0 = fg * 32;

    {
        float acc[32];
        #pragma unroll
        for (int j = 0; j < 32; ++j) acc[j] = mm_b1[F0 + j];
        for (int k = 0; k < DD; ++k) {
            float hv = bufA[e * 129 + k];
            const float* wk = mm_w1 + k * HH + F0;
            #pragma unroll
            for (int j = 0; j < 32; ++j) acc[j] = fmaf(hv, wk[j], acc[j]);
        }
        #pragma unroll
        for (int j = 0; j < 32; ++j) bufB[e * 129 + F0 + j] = silu_f(acc[j]);
    }
    __syncthreads();

    {
        float acc[32];
        #pragma unroll
        for (int j = 0; j < 32; ++j) acc[j] = mm_b2[F0 + j];
        for (int k = 0; k < HH; ++k) {
            float hv = bufB[e * 129 + k];
            const float* wk = mm_w2 + k * DD + F0;
            #pragma unroll
            for (int j = 0; j < 32; ++j) acc[j] = fmaf(hv, wk[j], acc[j]);
        }
        #pragma unroll
        for (int j = 0; j < 32; ++j) bufA[e * 129 + F0 + j] = acc[j];
    }
    __syncthreads();

    {
        const int f = tid & 127, ng = tid >> 7;
        for (int i = 0; i < 32; ++i) {
            int ln = ng * 32 + i, n = nb + ln;
            bufB[ln * 129 + f] = (n < N_NODES) ? xn[(size_t)n * DD + f] : 0.0f;
        }
    }
    __syncthreads();

    {
        float acc[32];
        #pragma unroll
        for (int j = 0; j < 32; ++j) acc[j] = sl_b[F0 + j] + ul_b[F0 + j];
        for (int k = 0; k < DD; ++k) {
            float a = bufB[e * 129 + k];
            float c = bufA[e * 129 + k];
            const float* wk1 = sl_w + k * DD + F0;
            const float* wk2 = ul_w + k * DD + F0;
            #pragma unroll
            for (int j = 0; j < 32; ++j) acc[j] = fmaf(a, wk1[j], acc[j]);
            #pragma unroll
            for (int j = 0; j < 32; ++j) acc[j] = fmaf(c, wk2[j], acc[j]);
        }
        __syncthreads();
        #pragma unroll
        for (int j = 0; j < 32; ++j) bufA[e * 129 + F0 + j] = acc[j];
    }
    __syncthreads();

    {
        float rs = res_scale[0];
        const int f = tid & 127, ng = tid >> 7;
        for (int i = 0; i < 32; ++i) {
            int ln = ng * 32 + i, n = nb + ln;
            if (n < N_NODES)
                out[(size_t)n * DD + f] = x[(size_t)n * DD + f] + rs * bufA[ln * 129 + f];
        }
    }
}

extern "C" void kernel_launch(void* const* d_in, const int* in_sizes, int n_in,
                              void* d_out, int out_size, void* d_ws, size_t ws_size,
                              hipStream_t stream) {
    const float* x     = (const float*)d_in[0];
    const int*   esrc  = (const int*)d_in[1];
    const int*   edst  = (const int*)d_in[2];
    // d_in[3] = edge_sh (unused)
    const float* rbf   = (const float*)d_in[4];
    const float* elen  = (const float*)d_in[5];
    const float* ln_g  = (const float*)d_in[6];
    const float* ln_b  = (const float*)d_in[7];
    const float* wm_w1 = (const float*)d_in[8];
    const float* wm_b1 = (const float*)d_in[9];
    const float* wm_w2 = (const float*)d_in[10];
    const float* wm_b2 = (const float*)d_in[11];
    const float* wm_w3 = (const float*)d_in[12];
    const float* wm_b3 = (const float*)d_in[13];
    const float* eg_w1 = (const float*)d_in[14];
    const float* eg_b1 = (const float*)d_in[15];
    const float* eg_w2 = (const float*)d_in[16];
    const float* eg_b2 = (const float*)d_in[17];
    const float* mm_w1 = (const float*)d_in[18];
    const float* mm_b1 = (const float*)d_in[19];
    const float* mm_w2 = (const float*)d_in[20];
    const float* mm_b2 = (const float*)d_in[21];
    const float* sl_w  = (const float*)d_in[22];
    const float* sl_b  = (const float*)d_in[23];
    const float* ul_w  = (const float*)d_in[24];
    const float* ul_b  = (const float*)d_in[25];
    const float* rscl  = (const float*)d_in[26];

    float* xn  = (float*)d_ws;
    float* agg = xn + (size_t)N_NODES * DD;
    float* nrm = agg + (size_t)N_NODES * DD;
    unsigned short* wp_eg1 = (unsigned short*)(nrm + N_NODES);
    unsigned short* wp_w1  = wp_eg1 + 4096;
    unsigned short* wp_w2  = wp_w1 + 4096;
    unsigned short* wp_w3  = wp_w2 + 16384;

    hipMemsetAsync(agg, 0, (size_t)(N_NODES * DD + N_NODES) * sizeof(float), stream);
    pack_w_kernel<<<16, 256, 0, stream>>>(eg_w1, wp_eg1, RR, HH);
    pack_w_kernel<<<16, 256, 0, stream>>>(wm_w1, wp_w1, RR, HH);
    pack_w_kernel<<<64, 256, 0, stream>>>(wm_w2, wp_w2, HH, HH);
    pack_w_kernel<<<64, 256, 0, stream>>>(wm_w3, wp_w3, HH, DD);
    ln_kernel<<<(N_NODES + 3) / 4, 256, 0, stream>>>(x, ln_g, ln_b, xn);
    edge_kernel<<<N_EDGES / 64, 256, 0, stream>>>(xn, esrc, edst, rbf, elen,
        wp_eg1, wp_w1, wp_w2, wp_w3,
        eg_b1, eg_w2, eg_b2, wm_b1, wm_b2, wm_b3, agg, nrm);
    node_kernel<<<(N_NODES + 63) / 64, 256, 0, stream>>>(x, xn, agg, nrm,
        mm_w1, mm_b1, mm_w2, mm_b2, sl_w, sl_b, ul_w, ul_b, rscl, (float*)d_out);
}

// Round 3
// 829.279 us; speedup vs baseline: 1.3606x; 1.0102x over previous
//
#include <hip/hip_runtime.h>
#include <math.h>

#define N_NODES 20000
#define N_EDGES 640000
#define DD 128
#define RR 32
#define HH 128
#define PI_F 3.14159265358979323846f

typedef short bf16x8 __attribute__((ext_vector_type(8)));
typedef float f32x4 __attribute__((ext_vector_type(4)));

__device__ __forceinline__ float silu_f(float x) { return x / (1.0f + __expf(-x)); }
__device__ __forceinline__ float sigmoid_f(float x) { return 1.0f / (1.0f + __expf(-x)); }
__device__ __forceinline__ unsigned short f2bf(float x) {
    unsigned u = __float_as_uint(x);
    return (unsigned short)((u + 0x7FFFu + ((u >> 16) & 1u)) >> 16);
}

// ---------------- weight pack: W[K][F] fp32 -> bf16 MFMA-A-fragment order ----
// packed[((s*NT + t)*64 + l)*8 + j] = W[s*32 + (l>>4)*8 + j][t*16 + (l&15)]
__global__ __launch_bounds__(256) void pack_w_kernel(const float* __restrict__ src,
                                                     unsigned short* __restrict__ dst,
                                                     int K, int F) {
    int o = blockIdx.x * 256 + threadIdx.x;
    if (o >= K * F) return;
    int NT = F >> 4;
    int j = o & 7;
    int l = (o >> 3) & 63;
    int rest = o >> 9;
    int t = rest % NT;
    int s = rest / NT;
    int k = s * 32 + ((l >> 4) << 3) + j;
    int f = t * 16 + (l & 15);
    dst[o] = f2bf(src[(size_t)k * F + f]);
}

// ---------------- LayerNorm: one wave per row ----------------
__global__ __launch_bounds__(256) void ln_kernel(const float* __restrict__ x,
                                                 const float* __restrict__ g,
                                                 const float* __restrict__ b,
                                                 float* __restrict__ xn) {
    int wid = (blockIdx.x * 256 + threadIdx.x) >> 6;
    int lane = threadIdx.x & 63;
    if (wid >= N_NODES) return;
    const float* row = x + (size_t)wid * DD;
    float v0 = row[lane], v1 = row[lane + 64];
    float s = v0 + v1, sq = v0 * v0 + v1 * v1;
    #pragma unroll
    for (int o = 32; o > 0; o >>= 1) { s += __shfl_xor(s, o); sq += __shfl_xor(sq, o); }
    float mu = s * (1.0f / 128.0f);
    float var = sq * (1.0f / 128.0f) - mu * mu;
    float inv = rsqrtf(var + 1e-5f);
    float* orow = xn + (size_t)wid * DD;
    orow[lane]      = (v0 - mu) * inv * g[lane]      + b[lane];
    orow[lane + 64] = (v1 - mu) * inv * g[lane + 64] + b[lane + 64];
}

// ---------------- grouping: histogram / scan / fill ----------------
__global__ __launch_bounds__(256) void hist_kernel(const int* __restrict__ edst,
                                                   const float* __restrict__ elen,
                                                   int* __restrict__ cnt) {
    int e = blockIdx.x * 256 + threadIdx.x;
    if (e >= N_EDGES) return;
    if (elen[e] <= 5.0f) atomicAdd(&cnt[edst[e]], 1);
}

__global__ __launch_bounds__(64) void scan_kernel(const int* __restrict__ cnt,
                                                  int* __restrict__ offs,
                                                  int* __restrict__ cursor) {
    const int lane = threadIdx.x;
    const int per = (N_NODES + 63) / 64;
    int s = 0;
    for (int i = 0; i < per; ++i) {
        int idx = lane * per + i;
        if (idx < N_NODES) s += cnt[idx];
    }
    int incl = s;
    #pragma unroll
    for (int o = 1; o < 64; o <<= 1) {
        int v = __shfl_up(incl, o);
        if (lane >= o) incl += v;
    }
    int run = incl - s;
    for (int i = 0; i < per; ++i) {
        int idx = lane * per + i;
        if (idx < N_NODES) {
            offs[idx] = run;
            cursor[idx] = run;
            run += cnt[idx];
        }
    }
    if (lane == 63) offs[N_NODES] = run;
}

__global__ __launch_bounds__(256) void fill_kernel(const int* __restrict__ edst,
                                                   const float* __restrict__ elen,
                                                   int* __restrict__ cursor,
                                                   int* __restrict__ perm) {
    int e = blockIdx.x * 256 + threadIdx.x;
    if (e >= N_EDGES) return;
    if (elen[e] <= 5.0f) {
        int pos = atomicAdd(&cursor[edst[e]], 1);
        perm[pos] = e;
    }
}

// ---------------- dst-major edge pipeline: one wave per destination node ----
// Per 16-edge tile: gate (8 MFMA) + L1 (8) + L2 (32) + L3 (32), swapped layout
// D[f][e]: lane(er=lane&15, kq=lane>>4) holds f = t*16+kq*4+r for edge er.
// Messages accumulate in registers across tiles; one shfl-reduce + plain store
// per node. NO fp32 atomics anywhere.
__global__ __launch_bounds__(256) void dst_kernel(
    const float* __restrict__ xn,
    const int* __restrict__ esrc,
    const float* __restrict__ rbf, const float* __restrict__ elen,
    const int* __restrict__ perm, const int* __restrict__ offs,
    const unsigned short* __restrict__ wp_eg1, const unsigned short* __restrict__ wp_w1,
    const unsigned short* __restrict__ wp_w2,  const unsigned short* __restrict__ wp_w3,
    const float* __restrict__ eg_b1, const float* __restrict__ eg_w2,
    const float* __restrict__ eg_b2,
    const float* __restrict__ wm_b1, const float* __restrict__ wm_b2,
    const float* __restrict__ wm_b3,
    float* __restrict__ agg)
{
    __shared__ unsigned short act[4][2][16 * 136];

    const int tid  = threadIdx.x;
    const int w    = tid >> 6;
    const int lane = tid & 63;
    const int er   = lane & 15;
    const int kq   = lane >> 4;
    const int n    = blockIdx.x * 4 + w;   // 20000 % 4 == 0

    const int base  = offs[n];
    const int count = offs[n + 1] - base;

    float acc[8][4];
    #pragma unroll
    for (int t = 0; t < 8; ++t)
        #pragma unroll
        for (int r = 0; r < 4; ++r) acc[t][r] = 0.0f;
    float ewsum = 0.0f;

    unsigned short* buf0 = &act[w][0][0];
    unsigned short* buf1 = &act[w][1][0];
    const float eb2 = eg_b2[0];

    for (int t0 = 0; t0 < count; t0 += 16) {
        const int idx = t0 + er;
        const bool valid = idx < count;
        const int e = perm[base + (valid ? idx : 0)];

        // B-frag of rbf: 8 consecutive k, fp32 -> bf16
        const float4* rp = (const float4*)(rbf + (size_t)e * RR + kq * 8);
        float4 r0 = rp[0], r1 = rp[1];
        bf16x8 bfr;
        bfr[0] = (short)f2bf(r0.x); bfr[1] = (short)f2bf(r0.y);
        bfr[2] = (short)f2bf(r0.z); bfr[3] = (short)f2bf(r0.w);
        bfr[4] = (short)f2bf(r1.x); bfr[5] = (short)f2bf(r1.y);
        bfr[6] = (short)f2bf(r1.z); bfr[7] = (short)f2bf(r1.w);

        const int src = esrc[e];
        const float len = elen[e];           // live edges have len <= CUTOFF
        const float cut = valid ? 0.5f * (__cosf(PI_F * len * 0.2f) + 1.0f) : 0.0f;

        // ---- gate: silu(rbf@eg_w1+b1) . eg_w2 ----
        float pdot = 0.0f;
        #pragma unroll
        for (int t = 0; t < 8; ++t) {
            bf16x8 af = *(const bf16x8*)(wp_eg1 + ((size_t)t * 64 + lane) * 8);
            f32x4 z = {0.f, 0.f, 0.f, 0.f};
            f32x4 c = __builtin_amdgcn_mfma_f32_16x16x32_bf16(af, bfr, z, 0, 0, 0);
            float4 b1 = *(const float4*)(eg_b1 + t * 16 + kq * 4);
            float4 w2 = *(const float4*)(eg_w2 + t * 16 + kq * 4);
            pdot += silu_f(c[0] + b1.x) * w2.x + silu_f(c[1] + b1.y) * w2.y
                  + silu_f(c[2] + b1.z) * w2.z + silu_f(c[3] + b1.w) * w2.w;
        }
        pdot += __shfl_xor(pdot, 16);
        pdot += __shfl_xor(pdot, 32);
        const float ew = cut * sigmoid_f(pdot + eb2);
        ewsum += ew;

        // ---- L1: buf0 = silu(rbf @ wm_w1 + b1) ----
        #pragma unroll
        for (int t = 0; t < 8; ++t) {
            bf16x8 af = *(const bf16x8*)(wp_w1 + ((size_t)t * 64 + lane) * 8);
            f32x4 z = {0.f, 0.f, 0.f, 0.f};
            f32x4 c = __builtin_amdgcn_mfma_f32_16x16x32_bf16(af, bfr, z, 0, 0, 0);
            float4 b1 = *(const float4*)(wm_b1 + t * 16 + kq * 4);
            unsigned h01 = (unsigned)f2bf(silu_f(c[0] + b1.x)) | ((unsigned)f2bf(silu_f(c[1] + b1.y)) << 16);
            unsigned h23 = (unsigned)f2bf(silu_f(c[2] + b1.z)) | ((unsigned)f2bf(silu_f(c[3] + b1.w)) << 16);
            *(uint2*)(buf0 + er * 136 + t * 16 + kq * 4) = make_uint2(h01, h23);
        }

        // ---- L2: buf1 = silu(buf0 @ wm_w2 + b2) ----
        bf16x8 bf[4];
        #pragma unroll
        for (int s = 0; s < 4; ++s)
            bf[s] = *(const bf16x8*)(buf0 + er * 136 + s * 32 + kq * 8);
        #pragma unroll
        for (int t = 0; t < 8; ++t) {
            f32x4 c = {0.f, 0.f, 0.f, 0.f};
            #pragma unroll
            for (int s = 0; s < 4; ++s) {
                bf16x8 af = *(const bf16x8*)(wp_w2 + (((size_t)s * 8 + t) * 64 + lane) * 8);
                c = __builtin_amdgcn_mfma_f32_16x16x32_bf16(af, bf[s], c, 0, 0, 0);
            }
            float4 b2 = *(const float4*)(wm_b2 + t * 16 + kq * 4);
            unsigned h01 = (unsigned)f2bf(silu_f(c[0] + b2.x)) | ((unsigned)f2bf(silu_f(c[1] + b2.y)) << 16);
            unsigned h23 = (unsigned)f2bf(silu_f(c[2] + b2.z)) | ((unsigned)f2bf(silu_f(c[3] + b2.w)) << 16);
            *(uint2*)(buf1 + er * 136 + t * 16 + kq * 4) = make_uint2(h01, h23);
        }

        // ---- L3 + gather + accumulate ----
        #pragma unroll
        for (int s = 0; s < 4; ++s)
            bf[s] = *(const bf16x8*)(buf1 + er * 136 + s * 32 + kq * 8);

        const float* xrow = xn + (size_t)src * DD;
        #pragma unroll
        for (int t = 0; t < 8; ++t) {
            f32x4 c = {0.f, 0.f, 0.f, 0.f};
            #pragma unroll
            for (int s = 0; s < 4; ++s) {
                bf16x8 af = *(const bf16x8*)(wp_w3 + (((size_t)s * 8 + t) * 64 + lane) * 8);
                c = __builtin_amdgcn_mfma_f32_16x16x32_bf16(af, bf[s], c, 0, 0, 0);
            }
            float4 b3 = *(const float4*)(wm_b3 + t * 16 + kq * 4);
            float4 xv = *(const float4*)(xrow + t * 16 + kq * 4);
            acc[t][0] += (c[0] + b3.x) * xv.x * ew;
            acc[t][1] += (c[1] + b3.y) * xv.y * ew;
            acc[t][2] += (c[2] + b3.z) * xv.z * ew;
            acc[t][3] += (c[3] + b3.w) * xv.w * ew;
        }
    }

    // ---- reduce over the 16 edge-lanes, normalize, store ----
    #pragma unroll
    for (int o = 1; o < 16; o <<= 1) ewsum += __shfl_xor(ewsum, o);
    const float inv = 1.0f / fmaxf(ewsum, 1e-8f);

    #pragma unroll
    for (int t = 0; t < 8; ++t)
        #pragma unroll
        for (int r = 0; r < 4; ++r) {
            #pragma unroll
            for (int o = 1; o < 16; o <<= 1) acc[t][r] += __shfl_xor(acc[t][r], o);
        }

    if (er == 0) {
        float* arow = agg + (size_t)n * DD;
        #pragma unroll
        for (int t = 0; t < 8; ++t) {
            float4 v = make_float4(acc[t][0] * inv, acc[t][1] * inv,
                                   acc[t][2] * inv, acc[t][3] * inv);
            *(float4*)(arow + t * 16 + kq * 4) = v;
        }
    }
}

// ---------------- Node finalize: 64 nodes per block (agg pre-normalized) ----
__global__ __launch_bounds__(256) void node_kernel(
    const float* __restrict__ x, const float* __restrict__ xn,
    const float* __restrict__ agg,
    const float* __restrict__ mm_w1, const float* __restrict__ mm_b1,
    const float* __restrict__ mm_w2, const float* __restrict__ mm_b2,
    const float* __restrict__ sl_w, const float* __restrict__ sl_b,
    const float* __restrict__ ul_w, const float* __restrict__ ul_b,
    const float* __restrict__ res_scale, float* __restrict__ out)
{
    __shared__ float bufA[64 * 129];
    __shared__ float bufB[64 * 129];

    const int tid = threadIdx.x;
    const int nb = blockIdx.x * 64;

    {
        const int f = tid & 127, ng = tid >> 7;
        for (int i = 0; i < 32; ++i) {
            int ln = ng * 32 + i, n = nb + ln;
            bufA[ln * 129 + f] = (n < N_NODES) ? agg[(size_t)n * DD + f] : 0.0f;
        }
    }
    __syncthreads();

    const int e  = tid & 63;
    const int fg = __builtin_amdgcn_readfirstlane(tid >> 6);
    const int F0 = fg * 32;

    {
        float acc[32];
        #pragma unroll
        for (int j = 0; j < 32; ++j) acc[j] = mm_b1[F0 + j];
        for (int k = 0; k < DD; ++k) {
            float hv = bufA[e * 129 + k];
            const float* wk = mm_w1 + k * HH + F0;
            #pragma unroll
            for (int j = 0; j < 32; ++j) acc[j] = fmaf(hv, wk[j], acc[j]);
        }
        #pragma unroll
        for (int j = 0; j < 32; ++j) bufB[e * 129 + F0 + j] = silu_f(acc[j]);
    }
    __syncthreads();

    {
        float acc[32];
        #pragma unroll
        for (int j = 0; j < 32; ++j) acc[j] = mm_b2[F0 + j];
        for (int k = 0; k < HH; ++k) {
            float hv = bufB[e * 129 + k];
            const float* wk = mm_w2 + k * DD + F0;
            #pragma unroll
            for (int j = 0; j < 32; ++j) acc[j] = fmaf(hv, wk[j], acc[j]);
        }
        #pragma unroll
        for (int j = 0; j < 32; ++j) bufA[e * 129 + F0 + j] = acc[j];
    }
    __syncthreads();

    {
        const int f = tid & 127, ng = tid >> 7;
        for (int i = 0; i < 32; ++i) {
            int ln = ng * 32 + i, n = nb + ln;
            bufB[ln * 129 + f] = (n < N_NODES) ? xn[(size_t)n * DD + f] : 0.0f;
        }
    }
    __syncthreads();

    {
        float acc[32];
        #pragma unroll
        for (int j = 0; j < 32; ++j) acc[j] = sl_b[F0 + j] + ul_b[F0 + j];
        for (int k = 0; k < DD; ++k) {
            float a = bufB[e * 129 + k];
            float c = bufA[e * 129 + k];
            const float* wk1 = sl_w + k * DD + F0;
            const float* wk2 = ul_w + k * DD + F0;
            #pragma unroll
            for (int j = 0; j < 32; ++j) acc[j] = fmaf(a, wk1[j], acc[j]);
            #pragma unroll
            for (int j = 0; j < 32; ++j) acc[j] = fmaf(c, wk2[j], acc[j]);
        }
        __syncthreads();
        #pragma unroll
        for (int j = 0; j < 32; ++j) bufA[e * 129 + F0 + j] = acc[j];
    }
    __syncthreads();

    {
        float rs = res_scale[0];
        const int f = tid & 127, ng = tid >> 7;
        for (int i = 0; i < 32; ++i) {
            int ln = ng * 32 + i, n = nb + ln;
            if (n < N_NODES)
                out[(size_t)n * DD + f] = x[(size_t)n * DD + f] + rs * bufA[ln * 129 + f];
        }
    }
}

extern "C" void kernel_launch(void* const* d_in, const int* in_sizes, int n_in,
                              void* d_out, int out_size, void* d_ws, size_t ws_size,
                              hipStream_t stream) {
    const float* x     = (const float*)d_in[0];
    const int*   esrc  = (const int*)d_in[1];
    const int*   edst  = (const int*)d_in[2];
    // d_in[3] = edge_sh (unused)
    const float* rbf   = (const float*)d_in[4];
    const float* elen  = (const float*)d_in[5];
    const float* ln_g  = (const float*)d_in[6];
    const float* ln_b  = (const float*)d_in[7];
    const float* wm_w1 = (const float*)d_in[8];
    const float* wm_b1 = (const float*)d_in[9];
    const float* wm_w2 = (const float*)d_in[10];
    const float* wm_b2 = (const float*)d_in[11];
    const float* wm_w3 = (const float*)d_in[12];
    const float* wm_b3 = (const float*)d_in[13];
    const float* eg_w1 = (const float*)d_in[14];
    const float* eg_b1 = (const float*)d_in[15];
    const float* eg_w2 = (const float*)d_in[16];
    const float* eg_b2 = (const float*)d_in[17];
    const float* mm_w1 = (const float*)d_in[18];
    const float* mm_b1 = (const float*)d_in[19];
    const float* mm_w2 = (const float*)d_in[20];
    const float* mm_b2 = (const float*)d_in[21];
    const float* sl_w  = (const float*)d_in[22];
    const float* sl_b  = (const float*)d_in[23];
    const float* ul_w  = (const float*)d_in[24];
    const float* ul_b  = (const float*)d_in[25];
    const float* rscl  = (const float*)d_in[26];

    float* xn  = (float*)d_ws;                                  // 2.56M f
    float* agg = xn + (size_t)N_NODES * DD;                     // 2.56M f
    unsigned short* wp_eg1 = (unsigned short*)(agg + (size_t)N_NODES * DD);
    unsigned short* wp_w1  = wp_eg1 + 4096;
    unsigned short* wp_w2  = wp_w1 + 4096;
    unsigned short* wp_w3  = wp_w2 + 16384;
    int* cnt    = (int*)(wp_w3 + 16384);
    int* offs   = cnt + N_NODES;
    int* cursor = offs + N_NODES + 1;
    int* perm   = cursor + N_NODES;

    hipMemsetAsync(cnt, 0, (size_t)N_NODES * sizeof(int), stream);
    pack_w_kernel<<<16, 256, 0, stream>>>(eg_w1, wp_eg1, RR, HH);
    pack_w_kernel<<<16, 256, 0, stream>>>(wm_w1, wp_w1, RR, HH);
    pack_w_kernel<<<64, 256, 0, stream>>>(wm_w2, wp_w2, HH, HH);
    pack_w_kernel<<<64, 256, 0, stream>>>(wm_w3, wp_w3, HH, DD);
    ln_kernel<<<(N_NODES + 3) / 4, 256, 0, stream>>>(x, ln_g, ln_b, xn);
    hist_kernel<<<N_EDGES / 256, 256, 0, stream>>>(edst, elen, cnt);
    scan_kernel<<<1, 64, 0, stream>>>(cnt, offs, cursor);
    fill_kernel<<<N_EDGES / 256, 256, 0, stream>>>(edst, elen, cursor, perm);
    dst_kernel<<<N_NODES / 4, 256, 0, stream>>>(xn, esrc, rbf, elen, perm, offs,
        wp_eg1, wp_w1, wp_w2, wp_w3,
        eg_b1, eg_w2, eg_b2, wm_b1, wm_b2, wm_b3, agg);
    node_kernel<<<(N_NODES + 63) / 64, 256, 0, stream>>>(x, xn, agg,
        mm_w1, mm_b1, mm_w2, mm_b2, sl_w, sl_b, ul_w, ul_b, rscl, (float*)d_out);
}

// Round 4
// 530.655 us; speedup vs baseline: 2.1263x; 1.5627x over previous
//
#include <hip/hip_runtime.h>
#include <math.h>

#define N_NODES 20000
#define N_EDGES 640000
#define DD 128
#define RR 32
#define HH 128
#define PI_F 3.14159265358979323846f

typedef short bf16x8 __attribute__((ext_vector_type(8)));
typedef float f32x4 __attribute__((ext_vector_type(4)));

__device__ __forceinline__ float silu_f(float x) { return x / (1.0f + __expf(-x)); }
__device__ __forceinline__ float sigmoid_f(float x) { return 1.0f / (1.0f + __expf(-x)); }
__device__ __forceinline__ unsigned short f2bf(float x) {
    unsigned u = __float_as_uint(x);
    return (unsigned short)((u + 0x7FFFu + ((u >> 16) & 1u)) >> 16);
}

// ---------------- weight pack: W[K][F] fp32 -> bf16 MFMA-A-fragment order ----
// packed[((s*NT + t)*64 + l)*8 + j] = W[s*32 + (l>>4)*8 + j][t*16 + (l&15)]
__global__ __launch_bounds__(256) void pack_w_kernel(const float* __restrict__ src,
                                                     unsigned short* __restrict__ dst,
                                                     int K, int F) {
    int o = blockIdx.x * 256 + threadIdx.x;
    if (o >= K * F) return;
    int NT = F >> 4;
    int j = o & 7;
    int l = (o >> 3) & 63;
    int rest = o >> 9;
    int t = rest % NT;
    int s = rest / NT;
    int k = s * 32 + ((l >> 4) << 3) + j;
    int f = t * 16 + (l & 15);
    dst[o] = f2bf(src[(size_t)k * F + f]);
}

// ---------------- LayerNorm: one wave per row ----------------
__global__ __launch_bounds__(256) void ln_kernel(const float* __restrict__ x,
                                                 const float* __restrict__ g,
                                                 const float* __restrict__ b,
                                                 float* __restrict__ xn) {
    int wid = (blockIdx.x * 256 + threadIdx.x) >> 6;
    int lane = threadIdx.x & 63;
    if (wid >= N_NODES) return;
    const float* row = x + (size_t)wid * DD;
    float v0 = row[lane], v1 = row[lane + 64];
    float s = v0 + v1, sq = v0 * v0 + v1 * v1;
    #pragma unroll
    for (int o = 32; o > 0; o >>= 1) { s += __shfl_xor(s, o); sq += __shfl_xor(sq, o); }
    float mu = s * (1.0f / 128.0f);
    float var = sq * (1.0f / 128.0f) - mu * mu;
    float inv = rsqrtf(var + 1e-5f);
    float* orow = xn + (size_t)wid * DD;
    orow[lane]      = (v0 - mu) * inv * g[lane]      + b[lane];
    orow[lane + 64] = (v1 - mu) * inv * g[lane + 64] + b[lane + 64];
}

// ---------------- grouping: histogram / scan / fill ----------------
__global__ __launch_bounds__(256) void hist_kernel(const int* __restrict__ edst,
                                                   const float* __restrict__ elen,
                                                   int* __restrict__ cnt) {
    int e = blockIdx.x * 256 + threadIdx.x;
    if (e >= N_EDGES) return;
    if (elen[e] <= 5.0f) atomicAdd(&cnt[edst[e]], 1);
}

__global__ __launch_bounds__(64) void scan_kernel(const int* __restrict__ cnt,
                                                  int* __restrict__ offs,
                                                  int* __restrict__ cursor) {
    const int lane = threadIdx.x;
    const int per = (N_NODES + 63) / 64;
    int s = 0;
    for (int i = 0; i < per; ++i) {
        int idx = lane * per + i;
        if (idx < N_NODES) s += cnt[idx];
    }
    int incl = s;
    #pragma unroll
    for (int o = 1; o < 64; o <<= 1) {
        int v = __shfl_up(incl, o);
        if (lane >= o) incl += v;
    }
    int run = incl - s;
    for (int i = 0; i < per; ++i) {
        int idx = lane * per + i;
        if (idx < N_NODES) {
            offs[idx] = run;
            cursor[idx] = run;
            run += cnt[idx];
        }
    }
    if (lane == 63) offs[N_NODES] = run;
}

__global__ __launch_bounds__(256) void fill_kernel(const int* __restrict__ edst,
                                                   const float* __restrict__ elen,
                                                   int* __restrict__ cursor,
                                                   int* __restrict__ perm) {
    int e = blockIdx.x * 256 + threadIdx.x;
    if (e >= N_EDGES) return;
    if (elen[e] <= 5.0f) {
        int pos = atomicAdd(&cursor[edst[e]], 1);
        perm[pos] = e;
    }
}

// ---------------- edge MLP + segmented scatter: 64 dst-sorted edges/block ----
// Phase A (per-wave, independent): MFMA MLP for 16 edges, swapped layout;
// message rows (ew pre-multiplied, fp32) overwrite the wave's own act region.
// Phase B (block): thread (f, half) walks 32 dst-sorted rows, one atomicAdd
// per segment boundary -> ~10x fewer fp32 atomics, block-level pre-reduction.
__global__ __launch_bounds__(256) void edge_seg_kernel(
    const float* __restrict__ xn,
    const int* __restrict__ esrc, const int* __restrict__ edst,
    const float* __restrict__ rbf, const float* __restrict__ elen,
    const int* __restrict__ perm, const int* __restrict__ nlive_p,
    const unsigned short* __restrict__ wp_eg1, const unsigned short* __restrict__ wp_w1,
    const unsigned short* __restrict__ wp_w2,  const unsigned short* __restrict__ wp_w3,
    const float* __restrict__ eg_b1, const float* __restrict__ eg_w2,
    const float* __restrict__ eg_b2,
    const float* __restrict__ wm_b1, const float* __restrict__ wm_b2,
    const float* __restrict__ wm_b3,
    float* __restrict__ agg, float* __restrict__ nrm)
{
    // per-wave region: 2 bf16 act buffers (2*16*136 ushort = 8704B);
    // after L3 operand reads it is reused as 16x132 f32 message rows (8448B)
    __shared__ unsigned short act[4][2][16 * 136];
    __shared__ float ew_s[64];
    __shared__ int   dst_s[64];

    const int nlive = nlive_p[0];
    if (blockIdx.x * 64 >= nlive) return;

    const int tid  = threadIdx.x;
    const int w    = tid >> 6;
    const int lane = tid & 63;
    const int er   = lane & 15;
    const int kq   = lane >> 4;

    const int gidx  = blockIdx.x * 64 + w * 16 + er;
    const bool valid = gidx < nlive;
    const int e = perm[valid ? gidx : nlive - 1];

    // B-frag of rbf: 8 consecutive k, fp32 -> bf16
    const float4* rp = (const float4*)(rbf + (size_t)e * RR + kq * 8);
    float4 r0 = rp[0], r1 = rp[1];
    bf16x8 bfr;
    bfr[0] = (short)f2bf(r0.x); bfr[1] = (short)f2bf(r0.y);
    bfr[2] = (short)f2bf(r0.z); bfr[3] = (short)f2bf(r0.w);
    bfr[4] = (short)f2bf(r1.x); bfr[5] = (short)f2bf(r1.y);
    bfr[6] = (short)f2bf(r1.z); bfr[7] = (short)f2bf(r1.w);

    const int src = esrc[e];
    const int dst = edst[e];
    const float len = elen[e];              // live edges have len <= CUTOFF
    const float cut = valid ? 0.5f * (__cosf(PI_F * len * 0.2f) + 1.0f) : 0.0f;

    // ---- gate: silu(rbf@eg_w1+b1) . eg_w2 ----
    float pdot = 0.0f;
    #pragma unroll
    for (int t = 0; t < 8; ++t) {
        bf16x8 af = *(const bf16x8*)(wp_eg1 + ((size_t)t * 64 + lane) * 8);
        f32x4 z = {0.f, 0.f, 0.f, 0.f};
        f32x4 c = __builtin_amdgcn_mfma_f32_16x16x32_bf16(af, bfr, z, 0, 0, 0);
        float4 b1 = *(const float4*)(eg_b1 + t * 16 + kq * 4);
        float4 w2 = *(const float4*)(eg_w2 + t * 16 + kq * 4);
        pdot += silu_f(c[0] + b1.x) * w2.x + silu_f(c[1] + b1.y) * w2.y
              + silu_f(c[2] + b1.z) * w2.z + silu_f(c[3] + b1.w) * w2.w;
    }
    pdot += __shfl_xor(pdot, 16);
    pdot += __shfl_xor(pdot, 32);
    const float ew = cut * sigmoid_f(pdot + eg_b2[0]);
    if (lane < 16) { ew_s[w * 16 + er] = ew; dst_s[w * 16 + er] = dst; }

    unsigned short* buf0 = &act[w][0][0];
    unsigned short* buf1 = &act[w][1][0];

    // ---- L1: buf0 = silu(rbf @ wm_w1 + b1) ----
    #pragma unroll
    for (int t = 0; t < 8; ++t) {
        bf16x8 af = *(const bf16x8*)(wp_w1 + ((size_t)t * 64 + lane) * 8);
        f32x4 z = {0.f, 0.f, 0.f, 0.f};
        f32x4 c = __builtin_amdgcn_mfma_f32_16x16x32_bf16(af, bfr, z, 0, 0, 0);
        float4 b1 = *(const float4*)(wm_b1 + t * 16 + kq * 4);
        unsigned h01 = (unsigned)f2bf(silu_f(c[0] + b1.x)) | ((unsigned)f2bf(silu_f(c[1] + b1.y)) << 16);
        unsigned h23 = (unsigned)f2bf(silu_f(c[2] + b1.z)) | ((unsigned)f2bf(silu_f(c[3] + b1.w)) << 16);
        *(uint2*)(buf0 + er * 136 + t * 16 + kq * 4) = make_uint2(h01, h23);
    }

    // ---- L2: buf1 = silu(buf0 @ wm_w2 + b2) ----
    bf16x8 bf[4];
    #pragma unroll
    for (int s = 0; s < 4; ++s)
        bf[s] = *(const bf16x8*)(buf0 + er * 136 + s * 32 + kq * 8);
    #pragma unroll
    for (int t = 0; t < 8; ++t) {
        f32x4 c = {0.f, 0.f, 0.f, 0.f};
        #pragma unroll
        for (int s = 0; s < 4; ++s) {
            bf16x8 af = *(const bf16x8*)(wp_w2 + (((size_t)s * 8 + t) * 64 + lane) * 8);
            c = __builtin_amdgcn_mfma_f32_16x16x32_bf16(af, bf[s], c, 0, 0, 0);
        }
        float4 b2 = *(const float4*)(wm_b2 + t * 16 + kq * 4);
        unsigned h01 = (unsigned)f2bf(silu_f(c[0] + b2.x)) | ((unsigned)f2bf(silu_f(c[1] + b2.y)) << 16);
        unsigned h23 = (unsigned)f2bf(silu_f(c[2] + b2.z)) | ((unsigned)f2bf(silu_f(c[3] + b2.w)) << 16);
        *(uint2*)(buf1 + er * 136 + t * 16 + kq * 4) = make_uint2(h01, h23);
    }

    // ---- L3 + gather + message write (reuses wave's act region as f32) ----
    #pragma unroll
    for (int s = 0; s < 4; ++s)
        bf[s] = *(const bf16x8*)(buf1 + er * 136 + s * 32 + kq * 8);

    float* msg = (float*)&act[w][0][0] + er * 132;   // 16 rows x 132 f32
    const float* xrow = xn + (size_t)src * DD;

    #pragma unroll
    for (int t = 0; t < 8; ++t) {
        f32x4 c = {0.f, 0.f, 0.f, 0.f};
        #pragma unroll
        for (int s = 0; s < 4; ++s) {
            bf16x8 af = *(const bf16x8*)(wp_w3 + (((size_t)s * 8 + t) * 64 + lane) * 8);
            c = __builtin_amdgcn_mfma_f32_16x16x32_bf16(af, bf[s], c, 0, 0, 0);
        }
        float4 b3 = *(const float4*)(wm_b3 + t * 16 + kq * 4);
        float4 xv = *(const float4*)(xrow + t * 16 + kq * 4);
        float4 v = make_float4((c[0] + b3.x) * xv.x * ew,
                               (c[1] + b3.y) * xv.y * ew,
                               (c[2] + b3.z) * xv.z * ew,
                               (c[3] + b3.w) * xv.w * ew);
        *(float4*)(msg + t * 16 + kq * 4) = v;
    }
    __syncthreads();

    // ---- Phase B: segmented reduce over 32 dst-sorted rows per half-block ----
    {
        const int f = tid & 127;
        const int g = tid >> 7;
        const float* msgb = (const float*)act;
        float run = 0.0f, ewrun = 0.0f;
        int cur = dst_s[g * 32];
        #pragma unroll 8
        for (int i = 0; i < 32; ++i) {
            const int row = g * 32 + i;
            const int d = dst_s[row];
            if (d != cur) {
                atomicAdd(&agg[(size_t)cur * DD + f], run);
                if (f == 0) atomicAdd(&nrm[cur], ewrun);
                run = 0.0f; ewrun = 0.0f; cur = d;
            }
            run += msgb[(row >> 4) * 2176 + (row & 15) * 132 + f];
            if (f == 0) ewrun += ew_s[row];
        }
        atomicAdd(&agg[(size_t)cur * DD + f], run);
        if (f == 0) atomicAdd(&nrm[cur], ewrun);
    }
}

// ---------------- Node finalize: 64 nodes per block ----------------
__global__ __launch_bounds__(256) void node_kernel(
    const float* __restrict__ x, const float* __restrict__ xn,
    const float* __restrict__ agg, const float* __restrict__ nrm,
    const float* __restrict__ mm_w1, const float* __restrict__ mm_b1,
    const float* __restrict__ mm_w2, const float* __restrict__ mm_b2,
    const float* __restrict__ sl_w, const float* __restrict__ sl_b,
    const float* __restrict__ ul_w, const float* __restrict__ ul_b,
    const float* __restrict__ res_scale, float* __restrict__ out)
{
    __shared__ float bufA[64 * 129];
    __shared__ float bufB[64 * 129];
    __shared__ float rs_s[64];

    const int tid = threadIdx.x;
    const int nb = blockIdx.x * 64;

    if (tid < 64) {
        int n = nb + tid;
        rs_s[tid] = (n < N_NODES) ? 1.0f / fmaxf(nrm[n], 1e-8f) : 0.0f;
    }
    __syncthreads();

    {
        const int f = tid & 127, ng = tid >> 7;
        for (int i = 0; i < 32; ++i) {
            int ln = ng * 32 + i, n = nb + ln;
            bufA[ln * 129 + f] = (n < N_NODES) ? agg[(size_t)n * DD + f] * rs_s[ln] : 0.0f;
        }
    }
    __syncthreads();

    const int e  = tid & 63;
    const int fg = __builtin_amdgcn_readfirstlane(tid >> 6);
    const int F0 = fg * 32;

    {
        float acc[32];
        #pragma unroll
        for (int j = 0; j < 32; ++j) acc[j] = mm_b1[F0 + j];
        for (int k = 0; k < DD; ++k) {
            float hv = bufA[e * 129 + k];
            const float* wk = mm_w1 + k * HH + F0;
            #pragma unroll
            for (int j = 0; j < 32; ++j) acc[j] = fmaf(hv, wk[j], acc[j]);
        }
        #pragma unroll
        for (int j = 0; j < 32; ++j) bufB[e * 129 + F0 + j] = silu_f(acc[j]);
    }
    __syncthreads();

    {
        float acc[32];
        #pragma unroll
        for (int j = 0; j < 32; ++j) acc[j] = mm_b2[F0 + j];
        for (int k = 0; k < HH; ++k) {
            float hv = bufB[e * 129 + k];
            const float* wk = mm_w2 + k * DD + F0;
            #pragma unroll
            for (int j = 0; j < 32; ++j) acc[j] = fmaf(hv, wk[j], acc[j]);
        }
        #pragma unroll
        for (int j = 0; j < 32; ++j) bufA[e * 129 + F0 + j] = acc[j];
    }
    __syncthreads();

    {
        const int f = tid & 127, ng = tid >> 7;
        for (int i = 0; i < 32; ++i) {
            int ln = ng * 32 + i, n = nb + ln;
            bufB[ln * 129 + f] = (n < N_NODES) ? xn[(size_t)n * DD + f] : 0.0f;
        }
    }
    __syncthreads();

    {
        float acc[32];
        #pragma unroll
        for (int j = 0; j < 32; ++j) acc[j] = sl_b[F0 + j] + ul_b[F0 + j];
        for (int k = 0; k < DD; ++k) {
            float a = bufB[e * 129 + k];
            float c = bufA[e * 129 + k];
            const float* wk1 = sl_w + k * DD + F0;
            const float* wk2 = ul_w + k * DD + F0;
            #pragma unroll
            for (int j = 0; j < 32; ++j) acc[j] = fmaf(a, wk1[j], acc[j]);
            #pragma unroll
            for (int j = 0; j < 32; ++j) acc[j] = fmaf(c, wk2[j], acc[j]);
        }
        __syncthreads();
        #pragma unroll
        for (int j = 0; j < 32; ++j) bufA[e * 129 + F0 + j] = acc[j];
    }
    __syncthreads();

    {
        float rs = res_scale[0];
        const int f = tid & 127, ng = tid >> 7;
        for (int i = 0; i < 32; ++i) {
            int ln = ng * 32 + i, n = nb + ln;
            if (n < N_NODES)
                out[(size_t)n * DD + f] = x[(size_t)n * DD + f] + rs * bufA[ln * 129 + f];
        }
    }
}

extern "C" void kernel_launch(void* const* d_in, const int* in_sizes, int n_in,
                              void* d_out, int out_size, void* d_ws, size_t ws_size,
                              hipStream_t stream) {
    const float* x     = (const float*)d_in[0];
    const int*   esrc  = (const int*)d_in[1];
    const int*   edst  = (const int*)d_in[2];
    // d_in[3] = edge_sh (unused)
    const float* rbf   = (const float*)d_in[4];
    const float* elen  = (const float*)d_in[5];
    const float* ln_g  = (const float*)d_in[6];
    const float* ln_b  = (const float*)d_in[7];
    const float* wm_w1 = (const float*)d_in[8];
    const float* wm_b1 = (const float*)d_in[9];
    const float* wm_w2 = (const float*)d_in[10];
    const float* wm_b2 = (const float*)d_in[11];
    const float* wm_w3 = (const float*)d_in[12];
    const float* wm_b3 = (const float*)d_in[13];
    const float* eg_w1 = (const float*)d_in[14];
    const float* eg_b1 = (const float*)d_in[15];
    const float* eg_w2 = (const float*)d_in[16];
    const float* eg_b2 = (const float*)d_in[17];
    const float* mm_w1 = (const float*)d_in[18];
    const float* mm_b1 = (const float*)d_in[19];
    const float* mm_w2 = (const float*)d_in[20];
    const float* mm_b2 = (const float*)d_in[21];
    const float* sl_w  = (const float*)d_in[22];
    const float* sl_b  = (const float*)d_in[23];
    const float* ul_w  = (const float*)d_in[24];
    const float* ul_b  = (const float*)d_in[25];
    const float* rscl  = (const float*)d_in[26];

    float* xn  = (float*)d_ws;                                  // 2.56M f
    float* agg = xn + (size_t)N_NODES * DD;                     // 2.56M f
    float* nrm = agg + (size_t)N_NODES * DD;                    // 20000 f
    unsigned short* wp_eg1 = (unsigned short*)(nrm + N_NODES);
    unsigned short* wp_w1  = wp_eg1 + 4096;
    unsigned short* wp_w2  = wp_w1 + 4096;
    unsigned short* wp_w3  = wp_w2 + 16384;
    int* cnt    = (int*)(wp_w3 + 16384);
    int* offs   = cnt + N_NODES;
    int* cursor = offs + N_NODES + 1;
    int* perm   = cursor + N_NODES;

    hipMemsetAsync(agg, 0, (size_t)(N_NODES * DD + N_NODES) * sizeof(float), stream);
    hipMemsetAsync(cnt, 0, (size_t)N_NODES * sizeof(int), stream);
    pack_w_kernel<<<16, 256, 0, stream>>>(eg_w1, wp_eg1, RR, HH);
    pack_w_kernel<<<16, 256, 0, stream>>>(wm_w1, wp_w1, RR, HH);
    pack_w_kernel<<<64, 256, 0, stream>>>(wm_w2, wp_w2, HH, HH);
    pack_w_kernel<<<64, 256, 0, stream>>>(wm_w3, wp_w3, HH, DD);
    ln_kernel<<<(N_NODES + 3) / 4, 256, 0, stream>>>(x, ln_g, ln_b, xn);
    hist_kernel<<<N_EDGES / 256, 256, 0, stream>>>(edst, elen, cnt);
    scan_kernel<<<1, 64, 0, stream>>>(cnt, offs, cursor);
    fill_kernel<<<N_EDGES / 256, 256, 0, stream>>>(edst, elen, cursor, perm);
    edge_seg_kernel<<<N_EDGES / 64, 256, 0, stream>>>(xn, esrc, edst, rbf, elen,
        perm, offs + N_NODES,
        wp_eg1, wp_w1, wp_w2, wp_w3,
        eg_b1, eg_w2, eg_b2, wm_b1, wm_b2, wm_b3, agg, nrm);
    node_kernel<<<(N_NODES + 63) / 64, 256, 0, stream>>>(x, xn, agg, nrm,
        mm_w1, mm_b1, mm_w2, mm_b2, sl_w, sl_b, ul_w, ul_b, rscl, (float*)d_out);
}

// Round 5
// 318.483 us; speedup vs baseline: 3.5428x; 1.6662x over previous
//
#include <hip/hip_runtime.h>
#include <math.h>

#define N_NODES 20000
#define N_EDGES 640000
#define DD 128
#define RR 32
#define HH 128
#define PI_F 3.14159265358979323846f

typedef short bf16x8 __attribute__((ext_vector_type(8)));
typedef float f32x4 __attribute__((ext_vector_type(4)));

__device__ __forceinline__ float silu_f(float x) { return x / (1.0f + __expf(-x)); }
__device__ __forceinline__ float sigmoid_f(float x) { return 1.0f / (1.0f + __expf(-x)); }
__device__ __forceinline__ unsigned short f2bf(float x) {
    unsigned u = __float_as_uint(x);
    return (unsigned short)((u + 0x7FFFu + ((u >> 16) & 1u)) >> 16);
}
__device__ __forceinline__ float bf2f(unsigned short u) {
    return __uint_as_float(((unsigned)u) << 16);
}

// ---------------- weight pack: W[K][F] fp32 -> bf16 MFMA-A-fragment order ----
// packed[((s*NT + t)*64 + l)*8 + j] = W[s*32 + (l>>4)*8 + j][t*16 + (l&15)]
__global__ __launch_bounds__(256) void pack_w_kernel(const float* __restrict__ src,
                                                     unsigned short* __restrict__ dst,
                                                     int K, int F) {
    int o = blockIdx.x * 256 + threadIdx.x;
    if (o >= K * F) return;
    int NT = F >> 4;
    int j = o & 7;
    int l = (o >> 3) & 63;
    int rest = o >> 9;
    int t = rest % NT;
    int s = rest / NT;
    int k = s * 32 + ((l >> 4) << 3) + j;
    int f = t * 16 + (l & 15);
    dst[o] = f2bf(src[(size_t)k * F + f]);
}

// ---------------- LayerNorm: one wave per row ----------------
__global__ __launch_bounds__(256) void ln_kernel(const float* __restrict__ x,
                                                 const float* __restrict__ g,
                                                 const float* __restrict__ b,
                                                 float* __restrict__ xn) {
    int wid = (blockIdx.x * 256 + threadIdx.x) >> 6;
    int lane = threadIdx.x & 63;
    if (wid >= N_NODES) return;
    const float* row = x + (size_t)wid * DD;
    float v0 = row[lane], v1 = row[lane + 64];
    float s = v0 + v1, sq = v0 * v0 + v1 * v1;
    #pragma unroll
    for (int o = 32; o > 0; o >>= 1) { s += __shfl_xor(s, o); sq += __shfl_xor(sq, o); }
    float mu = s * (1.0f / 128.0f);
    float var = sq * (1.0f / 128.0f) - mu * mu;
    float inv = rsqrtf(var + 1e-5f);
    float* orow = xn + (size_t)wid * DD;
    orow[lane]      = (v0 - mu) * inv * g[lane]      + b[lane];
    orow[lane + 64] = (v1 - mu) * inv * g[lane + 64] + b[lane + 64];
}

// ---------------- grouping: histogram / parallel scan / fill ----------------
__global__ __launch_bounds__(256) void hist_kernel(const int* __restrict__ edst,
                                                   const float* __restrict__ elen,
                                                   int* __restrict__ cnt) {
    int e = blockIdx.x * 256 + threadIdx.x;
    if (e >= N_EDGES) return;
    if (elen[e] <= 5.0f) atomicAdd(&cnt[edst[e]], 1);
}

__global__ __launch_bounds__(1024) void scan_kernel(const int* __restrict__ cnt,
                                                    int* __restrict__ offs,
                                                    int* __restrict__ cursor) {
    __shared__ int part[1024];
    const int t = threadIdx.x;
    const int per = 20;                       // 1024*20 >= 20000
    const int base = t * per;
    int s = 0;
    for (int i = 0; i < per; ++i) {
        int idx = base + i;
        if (idx < N_NODES) s += cnt[idx];
    }
    part[t] = s;
    __syncthreads();
    for (int off = 1; off < 1024; off <<= 1) {
        int v = (t >= off) ? part[t - off] : 0;
        __syncthreads();
        part[t] += v;
        __syncthreads();
    }
    int run = part[t] - s;                    // exclusive prefix
    for (int i = 0; i < per; ++i) {
        int idx = base + i;
        if (idx < N_NODES) {
            offs[idx] = run;
            cursor[idx] = run;
            run += cnt[idx];
        }
    }
    if (t == 1023) offs[N_NODES] = part[1023];
}

__global__ __launch_bounds__(256) void fill_kernel(const int* __restrict__ edst,
                                                   const float* __restrict__ elen,
                                                   int* __restrict__ cursor,
                                                   int* __restrict__ perm) {
    int e = blockIdx.x * 256 + threadIdx.x;
    if (e >= N_EDGES) return;
    if (elen[e] <= 5.0f) {
        int pos = atomicAdd(&cursor[edst[e]], 1);
        perm[pos] = e;
    }
}

// ---------------- edge MLP + segmented scatter: 128 dst-sorted edges/block ----
// 4 waves x 32 edges (two 16-edge MFMA B-groups per wave; each weight A-frag
// load feeds 2 MFMAs). Single act buffer/wave (frags pre-read into regs, then
// overwritten). Messages staged bf16 in the same buffer. One barrier total.
__global__ __launch_bounds__(256) void edge_seg_kernel(
    const float* __restrict__ xn,
    const int* __restrict__ esrc, const int* __restrict__ edst,
    const float* __restrict__ rbf, const float* __restrict__ elen,
    const int* __restrict__ perm, const int* __restrict__ nlive_p,
    const unsigned short* __restrict__ wp_eg1, const unsigned short* __restrict__ wp_w1,
    const unsigned short* __restrict__ wp_w2,  const unsigned short* __restrict__ wp_w3,
    const float* __restrict__ eg_b1, const float* __restrict__ eg_w2,
    const float* __restrict__ eg_b2,
    const float* __restrict__ wm_b1, const float* __restrict__ wm_b2,
    const float* __restrict__ wm_b3,
    float* __restrict__ agg, float* __restrict__ nrm)
{
    __shared__ unsigned short act[4][32 * 136];
    __shared__ float ew_s[128];
    __shared__ int   dst_s[128];

    const int nlive = nlive_p[0];
    if (blockIdx.x * 128 >= nlive) return;

    const int tid  = threadIdx.x;
    const int w    = tid >> 6;
    const int lane = tid & 63;
    const int er   = lane & 15;
    const int kq   = lane >> 4;

    const int g0 = blockIdx.x * 128 + w * 32 + er;
    const int g1 = g0 + 16;
    const bool v0 = g0 < nlive, v1 = g1 < nlive;
    const int e0 = perm[v0 ? g0 : nlive - 1];
    const int e1 = perm[v1 ? g1 : nlive - 1];

    // rbf B-frags (8 consecutive k per lane, fp32 -> bf16)
    bf16x8 bfr0, bfr1;
    {
        const float4* rp = (const float4*)(rbf + (size_t)e0 * RR + kq * 8);
        float4 a = rp[0], b = rp[1];
        bfr0[0]=(short)f2bf(a.x); bfr0[1]=(short)f2bf(a.y); bfr0[2]=(short)f2bf(a.z); bfr0[3]=(short)f2bf(a.w);
        bfr0[4]=(short)f2bf(b.x); bfr0[5]=(short)f2bf(b.y); bfr0[6]=(short)f2bf(b.z); bfr0[7]=(short)f2bf(b.w);
        const float4* rq = (const float4*)(rbf + (size_t)e1 * RR + kq * 8);
        float4 c = rq[0], d = rq[1];
        bfr1[0]=(short)f2bf(c.x); bfr1[1]=(short)f2bf(c.y); bfr1[2]=(short)f2bf(c.z); bfr1[3]=(short)f2bf(c.w);
        bfr1[4]=(short)f2bf(d.x); bfr1[5]=(short)f2bf(d.y); bfr1[6]=(short)f2bf(d.z); bfr1[7]=(short)f2bf(d.w);
    }

    const int src0 = esrc[e0], dst0 = edst[e0];
    const int src1 = esrc[e1], dst1 = edst[e1];
    const float len0 = elen[e0], len1 = elen[e1];
    const float cut0 = v0 ? 0.5f * (__cosf(PI_F * len0 * 0.2f) + 1.0f) : 0.0f;
    const float cut1 = v1 ? 0.5f * (__cosf(PI_F * len1 * 0.2f) + 1.0f) : 0.0f;

    // ---- gate ----
    float pd0 = 0.0f, pd1 = 0.0f;
    #pragma unroll
    for (int t = 0; t < 8; ++t) {
        bf16x8 af = *(const bf16x8*)(wp_eg1 + ((size_t)t * 64 + lane) * 8);
        f32x4 z = {0.f, 0.f, 0.f, 0.f};
        f32x4 c0 = __builtin_amdgcn_mfma_f32_16x16x32_bf16(af, bfr0, z, 0, 0, 0);
        f32x4 c1 = __builtin_amdgcn_mfma_f32_16x16x32_bf16(af, bfr1, z, 0, 0, 0);
        float4 b1 = *(const float4*)(eg_b1 + t * 16 + kq * 4);
        float4 w2 = *(const float4*)(eg_w2 + t * 16 + kq * 4);
        pd0 += silu_f(c0[0]+b1.x)*w2.x + silu_f(c0[1]+b1.y)*w2.y
             + silu_f(c0[2]+b1.z)*w2.z + silu_f(c0[3]+b1.w)*w2.w;
        pd1 += silu_f(c1[0]+b1.x)*w2.x + silu_f(c1[1]+b1.y)*w2.y
             + silu_f(c1[2]+b1.z)*w2.z + silu_f(c1[3]+b1.w)*w2.w;
    }
    pd0 += __shfl_xor(pd0, 16); pd0 += __shfl_xor(pd0, 32);
    pd1 += __shfl_xor(pd1, 16); pd1 += __shfl_xor(pd1, 32);
    const float eb2 = eg_b2[0];
    const float ew0 = cut0 * sigmoid_f(pd0 + eb2);
    const float ew1 = cut1 * sigmoid_f(pd1 + eb2);
    if (lane < 16) {
        ew_s[w * 32 + er] = ew0;       dst_s[w * 32 + er] = dst0;
        ew_s[w * 32 + 16 + er] = ew1;  dst_s[w * 32 + 16 + er] = dst1;
    }

    unsigned short* buf = &act[w][0];

    // ---- L1: buf = silu(rbf @ wm_w1 + b1) ----
    #pragma unroll
    for (int t = 0; t < 8; ++t) {
        bf16x8 af = *(const bf16x8*)(wp_w1 + ((size_t)t * 64 + lane) * 8);
        f32x4 z = {0.f, 0.f, 0.f, 0.f};
        f32x4 c0 = __builtin_amdgcn_mfma_f32_16x16x32_bf16(af, bfr0, z, 0, 0, 0);
        f32x4 c1 = __builtin_amdgcn_mfma_f32_16x16x32_bf16(af, bfr1, z, 0, 0, 0);
        float4 b1 = *(const float4*)(wm_b1 + t * 16 + kq * 4);
        unsigned a01 = (unsigned)f2bf(silu_f(c0[0]+b1.x)) | ((unsigned)f2bf(silu_f(c0[1]+b1.y)) << 16);
        unsigned a23 = (unsigned)f2bf(silu_f(c0[2]+b1.z)) | ((unsigned)f2bf(silu_f(c0[3]+b1.w)) << 16);
        unsigned b01 = (unsigned)f2bf(silu_f(c1[0]+b1.x)) | ((unsigned)f2bf(silu_f(c1[1]+b1.y)) << 16);
        unsigned b23 = (unsigned)f2bf(silu_f(c1[2]+b1.z)) | ((unsigned)f2bf(silu_f(c1[3]+b1.w)) << 16);
        *(uint2*)(buf + er * 136 + t * 16 + kq * 4)        = make_uint2(a01, a23);
        *(uint2*)(buf + (16 + er) * 136 + t * 16 + kq * 4) = make_uint2(b01, b23);
    }

    // ---- L2: read frags to regs, then overwrite buf in place ----
    bf16x8 h0[4], h1[4];
    #pragma unroll
    for (int s = 0; s < 4; ++s) {
        h0[s] = *(const bf16x8*)(buf + er * 136 + s * 32 + kq * 8);
        h1[s] = *(const bf16x8*)(buf + (16 + er) * 136 + s * 32 + kq * 8);
    }
    #pragma unroll
    for (int t = 0; t < 8; ++t) {
        f32x4 c0 = {0.f, 0.f, 0.f, 0.f};
        f32x4 c1 = {0.f, 0.f, 0.f, 0.f};
        #pragma unroll
        for (int s = 0; s < 4; ++s) {
            bf16x8 af = *(const bf16x8*)(wp_w2 + (((size_t)s * 8 + t) * 64 + lane) * 8);
            c0 = __builtin_amdgcn_mfma_f32_16x16x32_bf16(af, h0[s], c0, 0, 0, 0);
            c1 = __builtin_amdgcn_mfma_f32_16x16x32_bf16(af, h1[s], c1, 0, 0, 0);
        }
        float4 b2 = *(const float4*)(wm_b2 + t * 16 + kq * 4);
        unsigned a01 = (unsigned)f2bf(silu_f(c0[0]+b2.x)) | ((unsigned)f2bf(silu_f(c0[1]+b2.y)) << 16);
        unsigned a23 = (unsigned)f2bf(silu_f(c0[2]+b2.z)) | ((unsigned)f2bf(silu_f(c0[3]+b2.w)) << 16);
        unsigned b01 = (unsigned)f2bf(silu_f(c1[0]+b2.x)) | ((unsigned)f2bf(silu_f(c1[1]+b2.y)) << 16);
        unsigned b23 = (unsigned)f2bf(silu_f(c1[2]+b2.z)) | ((unsigned)f2bf(silu_f(c1[3]+b2.w)) << 16);
        *(uint2*)(buf + er * 136 + t * 16 + kq * 4)        = make_uint2(a01, a23);
        *(uint2*)(buf + (16 + er) * 136 + t * 16 + kq * 4) = make_uint2(b01, b23);
    }

    // ---- L3 + gather + bf16 message staging (in place) ----
    #pragma unroll
    for (int s = 0; s < 4; ++s) {
        h0[s] = *(const bf16x8*)(buf + er * 136 + s * 32 + kq * 8);
        h1[s] = *(const bf16x8*)(buf + (16 + er) * 136 + s * 32 + kq * 8);
    }
    const float* xr0 = xn + (size_t)src0 * DD;
    const float* xr1 = xn + (size_t)src1 * DD;
    #pragma unroll
    for (int t = 0; t < 8; ++t) {
        f32x4 c0 = {0.f, 0.f, 0.f, 0.f};
        f32x4 c1 = {0.f, 0.f, 0.f, 0.f};
        #pragma unroll
        for (int s = 0; s < 4; ++s) {
            bf16x8 af = *(const bf16x8*)(wp_w3 + (((size_t)s * 8 + t) * 64 + lane) * 8);
            c0 = __builtin_amdgcn_mfma_f32_16x16x32_bf16(af, h0[s], c0, 0, 0, 0);
            c1 = __builtin_amdgcn_mfma_f32_16x16x32_bf16(af, h1[s], c1, 0, 0, 0);
        }
        float4 b3 = *(const float4*)(wm_b3 + t * 16 + kq * 4);
        float4 xv0 = *(const float4*)(xr0 + t * 16 + kq * 4);
        float4 xv1 = *(const float4*)(xr1 + t * 16 + kq * 4);
        float m00 = (c0[0]+b3.x)*xv0.x*ew0, m01 = (c0[1]+b3.y)*xv0.y*ew0;
        float m02 = (c0[2]+b3.z)*xv0.z*ew0, m03 = (c0[3]+b3.w)*xv0.w*ew0;
        float m10 = (c1[0]+b3.x)*xv1.x*ew1, m11 = (c1[1]+b3.y)*xv1.y*ew1;
        float m12 = (c1[2]+b3.z)*xv1.z*ew1, m13 = (c1[3]+b3.w)*xv1.w*ew1;
        unsigned a01 = (unsigned)f2bf(m00) | ((unsigned)f2bf(m01) << 16);
        unsigned a23 = (unsigned)f2bf(m02) | ((unsigned)f2bf(m03) << 16);
        unsigned b01 = (unsigned)f2bf(m10) | ((unsigned)f2bf(m11) << 16);
        unsigned b23 = (unsigned)f2bf(m12) | ((unsigned)f2bf(m13) << 16);
        *(uint2*)(buf + er * 136 + t * 16 + kq * 4)        = make_uint2(a01, a23);
        *(uint2*)(buf + (16 + er) * 136 + t * 16 + kq * 4) = make_uint2(b01, b23);
    }
    __syncthreads();

    // ---- Phase B: segmented reduce over 64 dst-sorted rows per half-block ----
    {
        const int f = tid & 127;
        const int g = tid >> 7;
        float run = 0.0f, ewrun = 0.0f;
        int cur = dst_s[g * 64];
        for (int i = 0; i < 64; ++i) {
            const int row = g * 64 + i;
            const int d = dst_s[row];
            if (d != cur) {
                atomicAdd(&agg[(size_t)cur * DD + f], run);
                if (f == 0) atomicAdd(&nrm[cur], ewrun);
                run = 0.0f; ewrun = 0.0f; cur = d;
            }
            run += bf2f(act[row >> 5][(row & 31) * 136 + f]);
            if (f == 0) ewrun += ew_s[row];
        }
        atomicAdd(&agg[(size_t)cur * DD + f], run);
        if (f == 0) atomicAdd(&nrm[cur], ewrun);
    }
}

// ---------------- Node finalize (MFMA): 64 nodes/block, 16 per wave ----------
__global__ __launch_bounds__(256) void node_kernel(
    const float* __restrict__ x, const float* __restrict__ xn,
    const float* __restrict__ agg, const float* __restrict__ nrm,
    const unsigned short* __restrict__ wp_mm1, const unsigned short* __restrict__ wp_mm2,
    const unsigned short* __restrict__ wp_sl,  const unsigned short* __restrict__ wp_ul,
    const float* __restrict__ mm_b1, const float* __restrict__ mm_b2,
    const float* __restrict__ sl_b, const float* __restrict__ ul_b,
    const float* __restrict__ res_scale, float* __restrict__ out)
{
    __shared__ unsigned short act[4][16 * 136];

    const int tid  = threadIdx.x;
    const int w    = tid >> 6;
    const int lane = tid & 63;
    const int er   = lane & 15;
    const int kq   = lane >> 4;

    const int n  = blockIdx.x * 64 + w * 16 + er;
    const bool valid = n < N_NODES;
    const int nc = valid ? n : N_NODES - 1;

    const float rs = 1.0f / fmaxf(nrm[nc], 1e-8f);
    const float rscl = res_scale[0];

    // B-frags of normalized agg
    bf16x8 ba[4];
    #pragma unroll
    for (int s = 0; s < 4; ++s) {
        const float4* ap = (const float4*)(agg + (size_t)nc * DD + s * 32 + kq * 8);
        float4 a = ap[0], b = ap[1];
        ba[s][0]=(short)f2bf(a.x*rs); ba[s][1]=(short)f2bf(a.y*rs);
        ba[s][2]=(short)f2bf(a.z*rs); ba[s][3]=(short)f2bf(a.w*rs);
        ba[s][4]=(short)f2bf(b.x*rs); ba[s][5]=(short)f2bf(b.y*rs);
        ba[s][6]=(short)f2bf(b.z*rs); ba[s][7]=(short)f2bf(b.w*rs);
    }

    unsigned short* buf = &act[w][0];

    // mm1: buf = silu(agg_n @ mm_w1 + b1)
    #pragma unroll
    for (int t = 0; t < 8; ++t) {
        f32x4 c = {0.f, 0.f, 0.f, 0.f};
        #pragma unroll
        for (int s = 0; s < 4; ++s) {
            bf16x8 af = *(const bf16x8*)(wp_mm1 + (((size_t)s * 8 + t) * 64 + lane) * 8);
            c = __builtin_amdgcn_mfma_f32_16x16x32_bf16(af, ba[s], c, 0, 0, 0);
        }
        float4 b1 = *(const float4*)(mm_b1 + t * 16 + kq * 4);
        unsigned h01 = (unsigned)f2bf(silu_f(c[0]+b1.x)) | ((unsigned)f2bf(silu_f(c[1]+b1.y)) << 16);
        unsigned h23 = (unsigned)f2bf(silu_f(c[2]+b1.z)) | ((unsigned)f2bf(silu_f(c[3]+b1.w)) << 16);
        *(uint2*)(buf + er * 136 + t * 16 + kq * 4) = make_uint2(h01, h23);
    }

    // mm2: agg2 = buf @ mm_w2 + b2 (read frags, overwrite in place)
    bf16x8 bh[4];
    #pragma unroll
    for (int s = 0; s < 4; ++s)
        bh[s] = *(const bf16x8*)(buf + er * 136 + s * 32 + kq * 8);
    #pragma unroll
    for (int t = 0; t < 8; ++t) {
        f32x4 c = {0.f, 0.f, 0.f, 0.f};
        #pragma unroll
        for (int s = 0; s < 4; ++s) {
            bf16x8 af = *(const bf16x8*)(wp_mm2 + (((size_t)s * 8 + t) * 64 + lane) * 8);
            c = __builtin_amdgcn_mfma_f32_16x16x32_bf16(af, bh[s], c, 0, 0, 0);
        }
        float4 b2 = *(const float4*)(mm_b2 + t * 16 + kq * 4);
        unsigned h01 = (unsigned)f2bf(c[0]+b2.x) | ((unsigned)f2bf(c[1]+b2.y) << 16);
        unsigned h23 = (unsigned)f2bf(c[2]+b2.z) | ((unsigned)f2bf(c[3]+b2.w) << 16);
        *(uint2*)(buf + er * 136 + t * 16 + kq * 4) = make_uint2(h01, h23);
    }

    // frags of agg2 and xn
    bf16x8 bg[4], bx[4];
    #pragma unroll
    for (int s = 0; s < 4; ++s) {
        bg[s] = *(const bf16x8*)(buf + er * 136 + s * 32 + kq * 8);
        const float4* xp = (const float4*)(xn + (size_t)nc * DD + s * 32 + kq * 8);
        float4 a = xp[0], b = xp[1];
        bx[s][0]=(short)f2bf(a.x); bx[s][1]=(short)f2bf(a.y);
        bx[s][2]=(short)f2bf(a.z); bx[s][3]=(short)f2bf(a.w);
        bx[s][4]=(short)f2bf(b.x); bx[s][5]=(short)f2bf(b.y);
        bx[s][6]=(short)f2bf(b.z); bx[s][7]=(short)f2bf(b.w);
    }

    // out = x + rscl * (xn@sl_w + agg2@ul_w + sl_b + ul_b)
    #pragma unroll
    for (int t = 0; t < 8; ++t) {
        f32x4 c = {0.f, 0.f, 0.f, 0.f};
        #pragma unroll
        for (int s = 0; s < 4; ++s) {
            bf16x8 af = *(const bf16x8*)(wp_sl + (((size_t)s * 8 + t) * 64 + lane) * 8);
            c = __builtin_amdgcn_mfma_f32_16x16x32_bf16(af, bx[s], c, 0, 0, 0);
        }
        #pragma unroll
        for (int s = 0; s < 4; ++s) {
            bf16x8 af = *(const bf16x8*)(wp_ul + (((size_t)s * 8 + t) * 64 + lane) * 8);
            c = __builtin_amdgcn_mfma_f32_16x16x32_bf16(af, bg[s], c, 0, 0, 0);
        }
        if (valid) {
            float4 sb = *(const float4*)(sl_b + t * 16 + kq * 4);
            float4 ub = *(const float4*)(ul_b + t * 16 + kq * 4);
            float4 xv = *(const float4*)(x + (size_t)n * DD + t * 16 + kq * 4);
            float4 o;
            o.x = xv.x + rscl * (c[0] + sb.x + ub.x);
            o.y = xv.y + rscl * (c[1] + sb.y + ub.y);
            o.z = xv.z + rscl * (c[2] + sb.z + ub.z);
            o.w = xv.w + rscl * (c[3] + sb.w + ub.w);
            *(float4*)(out + (size_t)n * DD + t * 16 + kq * 4) = o;
        }
    }
}

extern "C" void kernel_launch(void* const* d_in, const int* in_sizes, int n_in,
                              void* d_out, int out_size, void* d_ws, size_t ws_size,
                              hipStream_t stream) {
    const float* x     = (const float*)d_in[0];
    const int*   esrc  = (const int*)d_in[1];
    const int*   edst  = (const int*)d_in[2];
    // d_in[3] = edge_sh (unused)
    const float* rbf   = (const float*)d_in[4];
    const float* elen  = (const float*)d_in[5];
    const float* ln_g  = (const float*)d_in[6];
    const float* ln_b  = (const float*)d_in[7];
    const float* wm_w1 = (const float*)d_in[8];
    const float* wm_b1 = (const float*)d_in[9];
    const float* wm_w2 = (const float*)d_in[10];
    const float* wm_b2 = (const float*)d_in[11];
    const float* wm_w3 = (const float*)d_in[12];
    const float* wm_b3 = (const float*)d_in[13];
    const float* eg_w1 = (const float*)d_in[14];
    const float* eg_b1 = (const float*)d_in[15];
    const float* eg_w2 = (const float*)d_in[16];
    const float* eg_b2 = (const float*)d_in[17];
    const float* mm_w1 = (const float*)d_in[18];
    const float* mm_b1 = (const float*)d_in[19];
    const float* mm_w2 = (const float*)d_in[20];
    const float* mm_b2 = (const float*)d_in[21];
    const float* sl_w  = (const float*)d_in[22];
    const float* sl_b  = (const float*)d_in[23];
    const float* ul_w  = (const float*)d_in[24];
    const float* ul_b  = (const float*)d_in[25];
    const float* rscl  = (const float*)d_in[26];

    float* xn  = (float*)d_ws;                                  // 2.56M f
    float* agg = xn + (size_t)N_NODES * DD;                     // 2.56M f
    float* nrm = agg + (size_t)N_NODES * DD;                    // 20000 f
    unsigned short* wp_eg1 = (unsigned short*)(nrm + N_NODES);
    unsigned short* wp_w1  = wp_eg1 + 4096;
    unsigned short* wp_w2  = wp_w1 + 4096;
    unsigned short* wp_w3  = wp_w2 + 16384;
    unsigned short* wp_mm1 = wp_w3 + 16384;
    unsigned short* wp_mm2 = wp_mm1 + 16384;
    unsigned short* wp_sl  = wp_mm2 + 16384;
    unsigned short* wp_ul  = wp_sl + 16384;
    int* cnt    = (int*)(wp_ul + 16384);
    int* offs   = cnt + N_NODES;
    int* cursor = offs + N_NODES + 1;
    int* perm   = cursor + N_NODES;

    hipMemsetAsync(agg, 0, (size_t)(N_NODES * DD + N_NODES) * sizeof(float), stream);
    hipMemsetAsync(cnt, 0, (size_t)N_NODES * sizeof(int), stream);
    pack_w_kernel<<<16, 256, 0, stream>>>(eg_w1, wp_eg1, RR, HH);
    pack_w_kernel<<<16, 256, 0, stream>>>(wm_w1, wp_w1, RR, HH);
    pack_w_kernel<<<64, 256, 0, stream>>>(wm_w2, wp_w2, HH, HH);
    pack_w_kernel<<<64, 256, 0, stream>>>(wm_w3, wp_w3, HH, DD);
    pack_w_kernel<<<64, 256, 0, stream>>>(mm_w1, wp_mm1, DD, HH);
    pack_w_kernel<<<64, 256, 0, stream>>>(mm_w2, wp_mm2, HH, DD);
    pack_w_kernel<<<64, 256, 0, stream>>>(sl_w, wp_sl, DD, DD);
    pack_w_kernel<<<64, 256, 0, stream>>>(ul_w, wp_ul, DD, DD);
    ln_kernel<<<(N_NODES + 3) / 4, 256, 0, stream>>>(x, ln_g, ln_b, xn);
    hist_kernel<<<N_EDGES / 256, 256, 0, stream>>>(edst, elen, cnt);
    scan_kernel<<<1, 1024, 0, stream>>>(cnt, offs, cursor);
    fill_kernel<<<N_EDGES / 256, 256, 0, stream>>>(edst, elen, cursor, perm);
    edge_seg_kernel<<<N_EDGES / 128, 256, 0, stream>>>(xn, esrc, edst, rbf, elen,
        perm, offs + N_NODES,
        wp_eg1, wp_w1, wp_w2, wp_w3,
        eg_b1, eg_w2, eg_b2, wm_b1, wm_b2, wm_b3, agg, nrm);
    node_kernel<<<(N_NODES + 63) / 64, 256, 0, stream>>>(x, xn, agg, nrm,
        wp_mm1, wp_mm2, wp_sl, wp_ul,
        mm_b1, mm_b2, sl_b, ul_b, rscl, (float*)d_out);
}

// Round 6
// 296.773 us; speedup vs baseline: 3.8019x; 1.0732x over previous
//
#include <hip/hip_runtime.h>
#include <math.h>

#define N_NODES 20000
#define N_EDGES 640000
#define DD 128
#define RR 32
#define HH 128
#define PI_F 3.14159265358979323846f

typedef short bf16x8 __attribute__((ext_vector_type(8)));
typedef float f32x4 __attribute__((ext_vector_type(4)));
typedef __bf16 bf16x2_t __attribute__((ext_vector_type(2)));

__device__ __forceinline__ float silu_f(float x) {
    return x * __builtin_amdgcn_rcpf(1.0f + __expf(-x));
}
__device__ __forceinline__ float sigmoid_f(float x) {
    return __builtin_amdgcn_rcpf(1.0f + __expf(-x));
}
__device__ __forceinline__ unsigned short f2bf(float x) {
    __bf16 h = (__bf16)x;
    return __builtin_bit_cast(unsigned short, h);
}
// two floats -> packed bf16 pair; ISel selects v_cvt_pk_bf16_f32
__device__ __forceinline__ unsigned pk2(float lo, float hi) {
    bf16x2_t v;
    v[0] = (__bf16)lo; v[1] = (__bf16)hi;
    return __builtin_bit_cast(unsigned, v);
}
__device__ __forceinline__ bf16x8 frag8(float4 a, float4 b) {
    union { unsigned u[4]; bf16x8 v; } r;
    r.u[0] = pk2(a.x, a.y); r.u[1] = pk2(a.z, a.w);
    r.u[2] = pk2(b.x, b.y); r.u[3] = pk2(b.z, b.w);
    return r.v;
}
__device__ __forceinline__ float bf2f(unsigned short u) {
    return __uint_as_float(((unsigned)u) << 16);
}

// ---------------- weight pack: W[K][F] fp32 -> bf16 MFMA-A-fragment order ----
// packed[((s*NT + t)*64 + l)*8 + j] = W[s*32 + (l>>4)*8 + j][t*16 + (l&15)]
__global__ __launch_bounds__(256) void pack_w_kernel(const float* __restrict__ src,
                                                     unsigned short* __restrict__ dst,
                                                     int K, int F) {
    int o = blockIdx.x * 256 + threadIdx.x;
    if (o >= K * F) return;
    int NT = F >> 4;
    int j = o & 7;
    int l = (o >> 3) & 63;
    int rest = o >> 9;
    int t = rest % NT;
    int s = rest / NT;
    int k = s * 32 + ((l >> 4) << 3) + j;
    int f = t * 16 + (l & 15);
    dst[o] = f2bf(src[(size_t)k * F + f]);
}

// ---------------- LayerNorm: one wave per row ----------------
__global__ __launch_bounds__(256) void ln_kernel(const float* __restrict__ x,
                                                 const float* __restrict__ g,
                                                 const float* __restrict__ b,
                                                 float* __restrict__ xn) {
    int wid = (blockIdx.x * 256 + threadIdx.x) >> 6;
    int lane = threadIdx.x & 63;
    if (wid >= N_NODES) return;
    const float* row = x + (size_t)wid * DD;
    float v0 = row[lane], v1 = row[lane + 64];
    float s = v0 + v1, sq = v0 * v0 + v1 * v1;
    #pragma unroll
    for (int o = 32; o > 0; o >>= 1) { s += __shfl_xor(s, o); sq += __shfl_xor(sq, o); }
    float mu = s * (1.0f / 128.0f);
    float var = sq * (1.0f / 128.0f) - mu * mu;
    float inv = rsqrtf(var + 1e-5f);
    float* orow = xn + (size_t)wid * DD;
    orow[lane]      = (v0 - mu) * inv * g[lane]      + b[lane];
    orow[lane + 64] = (v1 - mu) * inv * g[lane + 64] + b[lane + 64];
}

// ---------------- grouping: histogram / parallel scan / fill ----------------
__global__ __launch_bounds__(256) void hist_kernel(const int* __restrict__ edst,
                                                   const float* __restrict__ elen,
                                                   int* __restrict__ cnt) {
    int e = blockIdx.x * 256 + threadIdx.x;
    if (e >= N_EDGES) return;
    if (elen[e] <= 5.0f) atomicAdd(&cnt[edst[e]], 1);
}

__global__ __launch_bounds__(1024) void scan_kernel(const int* __restrict__ cnt,
                                                    int* __restrict__ offs,
                                                    int* __restrict__ cursor) {
    __shared__ int part[1024];
    const int t = threadIdx.x;
    const int per = 20;                       // 1024*20 >= 20000
    const int base = t * per;
    int s = 0;
    for (int i = 0; i < per; ++i) {
        int idx = base + i;
        if (idx < N_NODES) s += cnt[idx];
    }
    part[t] = s;
    __syncthreads();
    for (int off = 1; off < 1024; off <<= 1) {
        int v = (t >= off) ? part[t - off] : 0;
        __syncthreads();
        part[t] += v;
        __syncthreads();
    }
    int run = part[t] - s;                    // exclusive prefix
    for (int i = 0; i < per; ++i) {
        int idx = base + i;
        if (idx < N_NODES) {
            offs[idx] = run;
            cursor[idx] = run;
            run += cnt[idx];
        }
    }
    if (t == 1023) offs[N_NODES] = part[1023];
}

__global__ __launch_bounds__(256) void fill_kernel(const int* __restrict__ edst,
                                                   const float* __restrict__ elen,
                                                   int* __restrict__ cursor,
                                                   int* __restrict__ perm) {
    int e = blockIdx.x * 256 + threadIdx.x;
    if (e >= N_EDGES) return;
    if (elen[e] <= 5.0f) {
        int pos = atomicAdd(&cursor[edst[e]], 1);
        perm[pos] = e;
    }
}

// ---------------- edge MLP + segmented scatter: 128 dst-sorted edges/block ----
// 4 waves x 32 edges (two 16-edge MFMA B-groups per wave; each weight A-frag
// load feeds 2 MFMAs). Single act buffer/wave. Messages staged bf16.
__global__ __launch_bounds__(256) void edge_seg_kernel(
    const float* __restrict__ xn,
    const int* __restrict__ esrc, const int* __restrict__ edst,
    const float* __restrict__ rbf, const float* __restrict__ elen,
    const int* __restrict__ perm, const int* __restrict__ nlive_p,
    const unsigned short* __restrict__ wp_eg1, const unsigned short* __restrict__ wp_w1,
    const unsigned short* __restrict__ wp_w2,  const unsigned short* __restrict__ wp_w3,
    const float* __restrict__ eg_b1, const float* __restrict__ eg_w2,
    const float* __restrict__ eg_b2,
    const float* __restrict__ wm_b1, const float* __restrict__ wm_b2,
    const float* __restrict__ wm_b3,
    float* __restrict__ agg, float* __restrict__ nrm)
{
    __shared__ unsigned short act[4][32 * 136];
    __shared__ float ew_s[128];
    __shared__ int   dst_s[128];

    const int nlive = nlive_p[0];
    if (blockIdx.x * 128 >= nlive) return;

    const int tid  = threadIdx.x;
    const int w    = tid >> 6;
    const int lane = tid & 63;
    const int er   = lane & 15;
    const int kq   = lane >> 4;

    const int g0 = blockIdx.x * 128 + w * 32 + er;
    const int g1 = g0 + 16;
    const bool v0 = g0 < nlive, v1 = g1 < nlive;
    const int e0 = perm[v0 ? g0 : nlive - 1];
    const int e1 = perm[v1 ? g1 : nlive - 1];

    // rbf B-frags (8 consecutive k per lane, fp32 -> bf16 via cvt_pk)
    const float4* rp = (const float4*)(rbf + (size_t)e0 * RR + kq * 8);
    bf16x8 bfr0 = frag8(rp[0], rp[1]);
    const float4* rq = (const float4*)(rbf + (size_t)e1 * RR + kq * 8);
    bf16x8 bfr1 = frag8(rq[0], rq[1]);

    const int src0 = esrc[e0], dst0 = edst[e0];
    const int src1 = esrc[e1], dst1 = edst[e1];
    const float len0 = elen[e0], len1 = elen[e1];
    const float cut0 = v0 ? 0.5f * (__cosf(PI_F * len0 * 0.2f) + 1.0f) : 0.0f;
    const float cut1 = v1 ? 0.5f * (__cosf(PI_F * len1 * 0.2f) + 1.0f) : 0.0f;

    // ---- gate ----
    float pd0 = 0.0f, pd1 = 0.0f;
    #pragma unroll
    for (int t = 0; t < 8; ++t) {
        bf16x8 af = *(const bf16x8*)(wp_eg1 + ((size_t)t * 64 + lane) * 8);
        f32x4 z = {0.f, 0.f, 0.f, 0.f};
        f32x4 c0 = __builtin_amdgcn_mfma_f32_16x16x32_bf16(af, bfr0, z, 0, 0, 0);
        f32x4 c1 = __builtin_amdgcn_mfma_f32_16x16x32_bf16(af, bfr1, z, 0, 0, 0);
        float4 b1 = *(const float4*)(eg_b1 + t * 16 + kq * 4);
        float4 w2 = *(const float4*)(eg_w2 + t * 16 + kq * 4);
        pd0 += silu_f(c0[0]+b1.x)*w2.x + silu_f(c0[1]+b1.y)*w2.y
             + silu_f(c0[2]+b1.z)*w2.z + silu_f(c0[3]+b1.w)*w2.w;
        pd1 += silu_f(c1[0]+b1.x)*w2.x + silu_f(c1[1]+b1.y)*w2.y
             + silu_f(c1[2]+b1.z)*w2.z + silu_f(c1[3]+b1.w)*w2.w;
    }
    pd0 += __shfl_xor(pd0, 16); pd0 += __shfl_xor(pd0, 32);
    pd1 += __shfl_xor(pd1, 16); pd1 += __shfl_xor(pd1, 32);
    const float eb2 = eg_b2[0];
    const float ew0 = cut0 * sigmoid_f(pd0 + eb2);
    const float ew1 = cut1 * sigmoid_f(pd1 + eb2);
    if (lane < 16) {
        ew_s[w * 32 + er] = ew0;       dst_s[w * 32 + er] = dst0;
        ew_s[w * 32 + 16 + er] = ew1;  dst_s[w * 32 + 16 + er] = dst1;
    }

    unsigned short* buf = &act[w][0];

    // ---- L1: buf = silu(rbf @ wm_w1 + b1) ----
    #pragma unroll
    for (int t = 0; t < 8; ++t) {
        bf16x8 af = *(const bf16x8*)(wp_w1 + ((size_t)t * 64 + lane) * 8);
        f32x4 z = {0.f, 0.f, 0.f, 0.f};
        f32x4 c0 = __builtin_amdgcn_mfma_f32_16x16x32_bf16(af, bfr0, z, 0, 0, 0);
        f32x4 c1 = __builtin_amdgcn_mfma_f32_16x16x32_bf16(af, bfr1, z, 0, 0, 0);
        float4 b1 = *(const float4*)(wm_b1 + t * 16 + kq * 4);
        *(uint2*)(buf + er * 136 + t * 16 + kq * 4) =
            make_uint2(pk2(silu_f(c0[0]+b1.x), silu_f(c0[1]+b1.y)),
                       pk2(silu_f(c0[2]+b1.z), silu_f(c0[3]+b1.w)));
        *(uint2*)(buf + (16 + er) * 136 + t * 16 + kq * 4) =
            make_uint2(pk2(silu_f(c1[0]+b1.x), silu_f(c1[1]+b1.y)),
                       pk2(silu_f(c1[2]+b1.z), silu_f(c1[3]+b1.w)));
    }

    // ---- L2: read frags to regs, then overwrite buf in place ----
    bf16x8 h0[4], h1[4];
    #pragma unroll
    for (int s = 0; s < 4; ++s) {
        h0[s] = *(const bf16x8*)(buf + er * 136 + s * 32 + kq * 8);
        h1[s] = *(const bf16x8*)(buf + (16 + er) * 136 + s * 32 + kq * 8);
    }
    #pragma unroll
    for (int t = 0; t < 8; ++t) {
        f32x4 c0 = {0.f, 0.f, 0.f, 0.f};
        f32x4 c1 = {0.f, 0.f, 0.f, 0.f};
        #pragma unroll
        for (int s = 0; s < 4; ++s) {
            bf16x8 af = *(const bf16x8*)(wp_w2 + (((size_t)s * 8 + t) * 64 + lane) * 8);
            c0 = __builtin_amdgcn_mfma_f32_16x16x32_bf16(af, h0[s], c0, 0, 0, 0);
            c1 = __builtin_amdgcn_mfma_f32_16x16x32_bf16(af, h1[s], c1, 0, 0, 0);
        }
        float4 b2 = *(const float4*)(wm_b2 + t * 16 + kq * 4);
        *(uint2*)(buf + er * 136 + t * 16 + kq * 4) =
            make_uint2(pk2(silu_f(c0[0]+b2.x), silu_f(c0[1]+b2.y)),
                       pk2(silu_f(c0[2]+b2.z), silu_f(c0[3]+b2.w)));
        *(uint2*)(buf + (16 + er) * 136 + t * 16 + kq * 4) =
            make_uint2(pk2(silu_f(c1[0]+b2.x), silu_f(c1[1]+b2.y)),
                       pk2(silu_f(c1[2]+b2.z), silu_f(c1[3]+b2.w)));
    }

    // ---- L3 + gather + bf16 message staging (in place) ----
    #pragma unroll
    for (int s = 0; s < 4; ++s) {
        h0[s] = *(const bf16x8*)(buf + er * 136 + s * 32 + kq * 8);
        h1[s] = *(const bf16x8*)(buf + (16 + er) * 136 + s * 32 + kq * 8);
    }
    const float* xr0 = xn + (size_t)src0 * DD;
    const float* xr1 = xn + (size_t)src1 * DD;
    #pragma unroll
    for (int t = 0; t < 8; ++t) {
        f32x4 c0 = {0.f, 0.f, 0.f, 0.f};
        f32x4 c1 = {0.f, 0.f, 0.f, 0.f};
        #pragma unroll
        for (int s = 0; s < 4; ++s) {
            bf16x8 af = *(const bf16x8*)(wp_w3 + (((size_t)s * 8 + t) * 64 + lane) * 8);
            c0 = __builtin_amdgcn_mfma_f32_16x16x32_bf16(af, h0[s], c0, 0, 0, 0);
            c1 = __builtin_amdgcn_mfma_f32_16x16x32_bf16(af, h1[s], c1, 0, 0, 0);
        }
        float4 b3 = *(const float4*)(wm_b3 + t * 16 + kq * 4);
        float4 xv0 = *(const float4*)(xr0 + t * 16 + kq * 4);
        float4 xv1 = *(const float4*)(xr1 + t * 16 + kq * 4);
        *(uint2*)(buf + er * 136 + t * 16 + kq * 4) =
            make_uint2(pk2((c0[0]+b3.x)*xv0.x*ew0, (c0[1]+b3.y)*xv0.y*ew0),
                       pk2((c0[2]+b3.z)*xv0.z*ew0, (c0[3]+b3.w)*xv0.w*ew0));
        *(uint2*)(buf + (16 + er) * 136 + t * 16 + kq * 4) =
            make_uint2(pk2((c1[0]+b3.x)*xv1.x*ew1, (c1[1]+b3.y)*xv1.y*ew1),
                       pk2((c1[2]+b3.z)*xv1.z*ew1, (c1[3]+b3.w)*xv1.w*ew1));
    }
    __syncthreads();

    // ---- Phase B: segmented reduce over 64 dst-sorted rows per half-block ----
    {
        const int f = tid & 127;
        const int g = tid >> 7;
        float run = 0.0f, ewrun = 0.0f;
        int cur = dst_s[g * 64];
        for (int i = 0; i < 64; ++i) {
            const int row = g * 64 + i;
            const int d = dst_s[row];
            if (d != cur) {
                atomicAdd(&agg[(size_t)cur * DD + f], run);
                if (f == 0) atomicAdd(&nrm[cur], ewrun);
                run = 0.0f; ewrun = 0.0f; cur = d;
            }
            run += bf2f(act[row >> 5][(row & 31) * 136 + f]);
            if (f == 0) ewrun += ew_s[row];
        }
        atomicAdd(&agg[(size_t)cur * DD + f], run);
        if (f == 0) atomicAdd(&nrm[cur], ewrun);
    }
}

// ---------------- Node finalize (MFMA): 64 nodes/block, 16 per wave ----------
__global__ __launch_bounds__(256) void node_kernel(
    const float* __restrict__ x, const float* __restrict__ xn,
    const float* __restrict__ agg, const float* __restrict__ nrm,
    const unsigned short* __restrict__ wp_mm1, const unsigned short* __restrict__ wp_mm2,
    const unsigned short* __restrict__ wp_sl,  const unsigned short* __restrict__ wp_ul,
    const float* __restrict__ mm_b1, const float* __restrict__ mm_b2,
    const float* __restrict__ sl_b, const float* __restrict__ ul_b,
    const float* __restrict__ res_scale, float* __restrict__ out)
{
    __shared__ unsigned short act[4][16 * 136];

    const int tid  = threadIdx.x;
    const int w    = tid >> 6;
    const int lane = tid & 63;
    const int er   = lane & 15;
    const int kq   = lane >> 4;

    const int n  = blockIdx.x * 64 + w * 16 + er;
    const bool valid = n < N_NODES;
    const int nc = valid ? n : N_NODES - 1;

    const float rs = __builtin_amdgcn_rcpf(fmaxf(nrm[nc], 1e-8f));
    const float rscl = res_scale[0];

    // B-frags of normalized agg
    bf16x8 ba[4];
    #pragma unroll
    for (int s = 0; s < 4; ++s) {
        const float4* ap = (const float4*)(agg + (size_t)nc * DD + s * 32 + kq * 8);
        float4 a = ap[0], b = ap[1];
        a.x *= rs; a.y *= rs; a.z *= rs; a.w *= rs;
        b.x *= rs; b.y *= rs; b.z *= rs; b.w *= rs;
        ba[s] = frag8(a, b);
    }

    unsigned short* buf = &act[w][0];

    // mm1: buf = silu(agg_n @ mm_w1 + b1)
    #pragma unroll
    for (int t = 0; t < 8; ++t) {
        f32x4 c = {0.f, 0.f, 0.f, 0.f};
        #pragma unroll
        for (int s = 0; s < 4; ++s) {
            bf16x8 af = *(const bf16x8*)(wp_mm1 + (((size_t)s * 8 + t) * 64 + lane) * 8);
            c = __builtin_amdgcn_mfma_f32_16x16x32_bf16(af, ba[s], c, 0, 0, 0);
        }
        float4 b1 = *(const float4*)(mm_b1 + t * 16 + kq * 4);
        *(uint2*)(buf + er * 136 + t * 16 + kq * 4) =
            make_uint2(pk2(silu_f(c[0]+b1.x), silu_f(c[1]+b1.y)),
                       pk2(silu_f(c[2]+b1.z), silu_f(c[3]+b1.w)));
    }

    // mm2: agg2 = buf @ mm_w2 + b2 (read frags, overwrite in place)
    bf16x8 bh[4];
    #pragma unroll
    for (int s = 0; s < 4; ++s)
        bh[s] = *(const bf16x8*)(buf + er * 136 + s * 32 + kq * 8);
    #pragma unroll
    for (int t = 0; t < 8; ++t) {
        f32x4 c = {0.f, 0.f, 0.f, 0.f};
        #pragma unroll
        for (int s = 0; s < 4; ++s) {
            bf16x8 af = *(const bf16x8*)(wp_mm2 + (((size_t)s * 8 + t) * 64 + lane) * 8);
            c = __builtin_amdgcn_mfma_f32_16x16x32_bf16(af, bh[s], c, 0, 0, 0);
        }
        float4 b2 = *(const float4*)(mm_b2 + t * 16 + kq * 4);
        *(uint2*)(buf + er * 136 + t * 16 + kq * 4) =
            make_uint2(pk2(c[0]+b2.x, c[1]+b2.y), pk2(c[2]+b2.z, c[3]+b2.w));
    }

    // frags of agg2 and xn
    bf16x8 bg[4], bx[4];
    #pragma unroll
    for (int s = 0; s < 4; ++s) {
        bg[s] = *(const bf16x8*)(buf + er * 136 + s * 32 + kq * 8);
        const float4* xp = (const float4*)(xn + (size_t)nc * DD + s * 32 + kq * 8);
        bx[s] = frag8(xp[0], xp[1]);
    }

    // out = x + rscl * (xn@sl_w + agg2@ul_w + sl_b + ul_b)
    #pragma unroll
    for (int t = 0; t < 8; ++t) {
        f32x4 c = {0.f, 0.f, 0.f, 0.f};
        #pragma unroll
        for (int s = 0; s < 4; ++s) {
            bf16x8 af = *(const bf16x8*)(wp_sl + (((size_t)s * 8 + t) * 64 + lane) * 8);
            c = __builtin_amdgcn_mfma_f32_16x16x32_bf16(af, bx[s], c, 0, 0, 0);
        }
        #pragma unroll
        for (int s = 0; s < 4; ++s) {
            bf16x8 af = *(const bf16x8*)(wp_ul + (((size_t)s * 8 + t) * 64 + lane) * 8);
            c = __builtin_amdgcn_mfma_f32_16x16x32_bf16(af, bg[s], c, 0, 0, 0);
        }
        if (valid) {
            float4 sb = *(const float4*)(sl_b + t * 16 + kq * 4);
            float4 ub = *(const float4*)(ul_b + t * 16 + kq * 4);
            float4 xv = *(const float4*)(x + (size_t)n * DD + t * 16 + kq * 4);
            float4 o;
            o.x = xv.x + rscl * (c[0] + sb.x + ub.x);
            o.y = xv.y + rscl * (c[1] + sb.y + ub.y);
            o.z = xv.z + rscl * (c[2] + sb.z + ub.z);
            o.w = xv.w + rscl * (c[3] + sb.w + ub.w);
            *(float4*)(out + (size_t)n * DD + t * 16 + kq * 4) = o;
        }
    }
}

extern "C" void kernel_launch(void* const* d_in, const int* in_sizes, int n_in,
                              void* d_out, int out_size, void* d_ws, size_t ws_size,
                              hipStream_t stream) {
    const float* x     = (const float*)d_in[0];
    const int*   esrc  = (const int*)d_in[1];
    const int*   edst  = (const int*)d_in[2];
    // d_in[3] = edge_sh (unused)
    const float* rbf   = (const float*)d_in[4];
    const float* elen  = (const float*)d_in[5];
    const float* ln_g  = (const float*)d_in[6];
    const float* ln_b  = (const float*)d_in[7];
    const float* wm_w1 = (const float*)d_in[8];
    const float* wm_b1 = (const float*)d_in[9];
    const float* wm_w2 = (const float*)d_in[10];
    const float* wm_b2 = (const float*)d_in[11];
    const float* wm_w3 = (const float*)d_in[12];
    const float* wm_b3 = (const float*)d_in[13];
    const float* eg_w1 = (const float*)d_in[14];
    const float* eg_b1 = (const float*)d_in[15];
    const float* eg_w2 = (const float*)d_in[16];
    const float* eg_b2 = (const float*)d_in[17];
    const float* mm_w1 = (const float*)d_in[18];
    const float* mm_b1 = (const float*)d_in[19];
    const float* mm_w2 = (const float*)d_in[20];
    const float* mm_b2 = (const float*)d_in[21];
    const float* sl_w  = (const float*)d_in[22];
    const float* sl_b  = (const float*)d_in[23];
    const float* ul_w  = (const float*)d_in[24];
    const float* ul_b  = (const float*)d_in[25];
    const float* rscl  = (const float*)d_in[26];

    float* xn  = (float*)d_ws;                                  // 2.56M f
    float* agg = xn + (size_t)N_NODES * DD;                     // 2.56M f
    float* nrm = agg + (size_t)N_NODES * DD;                    // 20000 f
    unsigned short* wp_eg1 = (unsigned short*)(nrm + N_NODES);
    unsigned short* wp_w1  = wp_eg1 + 4096;
    unsigned short* wp_w2  = wp_w1 + 4096;
    unsigned short* wp_w3  = wp_w2 + 16384;
    unsigned short* wp_mm1 = wp_w3 + 16384;
    unsigned short* wp_mm2 = wp_mm1 + 16384;
    unsigned short* wp_sl  = wp_mm2 + 16384;
    unsigned short* wp_ul  = wp_sl + 16384;
    int* cnt    = (int*)(wp_ul + 16384);
    int* offs   = cnt + N_NODES;
    int* cursor = offs + N_NODES + 1;
    int* perm   = cursor + N_NODES;

    hipMemsetAsync(agg, 0, (size_t)(N_NODES * DD + N_NODES) * sizeof(float), stream);
    hipMemsetAsync(cnt, 0, (size_t)N_NODES * sizeof(int), stream);
    pack_w_kernel<<<16, 256, 0, stream>>>(eg_w1, wp_eg1, RR, HH);
    pack_w_kernel<<<16, 256, 0, stream>>>(wm_w1, wp_w1, RR, HH);
    pack_w_kernel<<<64, 256, 0, stream>>>(wm_w2, wp_w2, HH, HH);
    pack_w_kernel<<<64, 256, 0, stream>>>(wm_w3, wp_w3, HH, DD);
    pack_w_kernel<<<64, 256, 0, stream>>>(mm_w1, wp_mm1, DD, HH);
    pack_w_kernel<<<64, 256, 0, stream>>>(mm_w2, wp_mm2, HH, DD);
    pack_w_kernel<<<64, 256, 0, stream>>>(sl_w, wp_sl, DD, DD);
    pack_w_kernel<<<64, 256, 0, stream>>>(ul_w, wp_ul, DD, DD);
    ln_kernel<<<(N_NODES + 3) / 4, 256, 0, stream>>>(x, ln_g, ln_b, xn);
    hist_kernel<<<N_EDGES / 256, 256, 0, stream>>>(edst, elen, cnt);
    scan_kernel<<<1, 1024, 0, stream>>>(cnt, offs, cursor);
    fill_kernel<<<N_EDGES / 256, 256, 0, stream>>>(edst, elen, cursor, perm);
    edge_seg_kernel<<<N_EDGES / 128, 256, 0, stream>>>(xn, esrc, edst, rbf, elen,
        perm, offs + N_NODES,
        wp_eg1, wp_w1, wp_w2, wp_w3,
        eg_b1, eg_w2, eg_b2, wm_b1, wm_b2, wm_b3, agg, nrm);
    node_kernel<<<(N_NODES + 63) / 64, 256, 0, stream>>>(x, xn, agg, nrm,
        wp_mm1, wp_mm2, wp_sl, wp_ul,
        mm_b1, mm_b2, sl_b, ul_b, rscl, (float*)d_out);
}

// Round 7
// 243.005 us; speedup vs baseline: 4.6431x; 1.2213x over previous
//
#include <hip/hip_runtime.h>
#include <math.h>

#define N_NODES 20000
#define N_EDGES 640000
#define DD 128
#define RR 32
#define HH 128
#define PI_F 3.14159265358979323846f

// prep_kernel block ranges
#define NPACK 416      // 106496 packed weights / 256
#define NLN   5000     // 20000 nodes / 4 rows per block
#define NHIST 2500     // 640000 edges / 256

typedef short bf16x8 __attribute__((ext_vector_type(8)));
typedef float f32x4 __attribute__((ext_vector_type(4)));
typedef __bf16 bf16x2_t __attribute__((ext_vector_type(2)));

__device__ __forceinline__ float silu_f(float x) {
    return x * __builtin_amdgcn_rcpf(1.0f + __expf(-x));
}
__device__ __forceinline__ float sigmoid_f(float x) {
    return __builtin_amdgcn_rcpf(1.0f + __expf(-x));
}
__device__ __forceinline__ unsigned short f2bf(float x) {
    __bf16 h = (__bf16)x;
    return __builtin_bit_cast(unsigned short, h);
}
// two floats -> packed bf16 pair; ISel selects v_cvt_pk_bf16_f32
__device__ __forceinline__ unsigned pk2(float lo, float hi) {
    bf16x2_t v;
    v[0] = (__bf16)lo; v[1] = (__bf16)hi;
    return __builtin_bit_cast(unsigned, v);
}
__device__ __forceinline__ bf16x8 frag8(float4 a, float4 b) {
    union { unsigned u[4]; bf16x8 v; } r;
    r.u[0] = pk2(a.x, a.y); r.u[1] = pk2(a.z, a.w);
    r.u[2] = pk2(b.x, b.y); r.u[3] = pk2(b.z, b.w);
    return r.v;
}

// pack W[K][F] fp32 -> bf16 MFMA-A-fragment order:
// packed[((s*NT + t)*64 + l)*8 + j] = W[s*32 + (l>>4)*8 + j][t*16 + (l&15)]
__device__ __forceinline__ unsigned short pack_one(const float* __restrict__ src,
                                                   int o, int F) {
    int NT = F >> 4;
    int j = o & 7;
    int l = (o >> 3) & 63;
    int rest = o >> 9;
    int t = rest % NT;
    int s = rest / NT;
    int k = s * 32 + ((l >> 4) << 3) + j;
    int f = t * 16 + (l & 15);
    return f2bf(src[(size_t)k * F + f]);
}

// ---------------- prep: weight packs + LayerNorm + histogram in one launch ---
__global__ __launch_bounds__(256) void prep_kernel(
    // pack srcs
    const float* __restrict__ eg_w1, const float* __restrict__ wm_w1,
    const float* __restrict__ wm_w2, const float* __restrict__ wm_w3,
    const float* __restrict__ mm_w1, const float* __restrict__ mm_w2,
    const float* __restrict__ sl_w,  const float* __restrict__ ul_w,
    unsigned short* __restrict__ wp,       // contiguous 106496 ushort
    // LN
    const float* __restrict__ x, const float* __restrict__ g,
    const float* __restrict__ b, float* __restrict__ xn,
    // hist
    const int* __restrict__ edst, const float* __restrict__ elen,
    int* __restrict__ cnt)
{
    const int blk = blockIdx.x;
    if (blk < NPACK) {
        int o = blk * 256 + threadIdx.x;
        unsigned short v;
        if      (o < 4096)   v = pack_one(eg_w1, o,          HH);
        else if (o < 8192)   v = pack_one(wm_w1, o - 4096,   HH);
        else if (o < 24576)  v = pack_one(wm_w2, o - 8192,   HH);
        else if (o < 40960)  v = pack_one(wm_w3, o - 24576,  DD);
        else if (o < 57344)  v = pack_one(mm_w1, o - 40960,  HH);
        else if (o < 73728)  v = pack_one(mm_w2, o - 57344,  DD);
        else if (o < 90112)  v = pack_one(sl_w,  o - 73728,  DD);
        else                 v = pack_one(ul_w,  o - 90112,  DD);
        wp[o] = v;
    } else if (blk < NPACK + NLN) {
        int wid = ((blk - NPACK) * 256 + threadIdx.x) >> 6;
        int lane = threadIdx.x & 63;
        if (wid >= N_NODES) return;
        const float* row = x + (size_t)wid * DD;
        float v0 = row[lane], v1 = row[lane + 64];
        float s = v0 + v1, sq = v0 * v0 + v1 * v1;
        #pragma unroll
        for (int o = 32; o > 0; o >>= 1) { s += __shfl_xor(s, o); sq += __shfl_xor(sq, o); }
        float mu = s * (1.0f / 128.0f);
        float var = sq * (1.0f / 128.0f) - mu * mu;
        float inv = rsqrtf(var + 1e-5f);
        float* orow = xn + (size_t)wid * DD;
        orow[lane]      = (v0 - mu) * inv * g[lane]      + b[lane];
        orow[lane + 64] = (v1 - mu) * inv * g[lane + 64] + b[lane + 64];
    } else {
        int e = (blk - NPACK - NLN) * 256 + threadIdx.x;
        if (e < N_EDGES && elen[e] <= 5.0f) atomicAdd(&cnt[edst[e]], 1);
    }
}

// ---------------- parallel scan over node counts ----------------
__global__ __launch_bounds__(1024) void scan_kernel(const int* __restrict__ cnt,
                                                    int* __restrict__ offs,
                                                    int* __restrict__ cursor) {
    __shared__ int part[1024];
    const int t = threadIdx.x;
    const int per = 20;                       // 1024*20 >= 20000
    const int base = t * per;
    int s = 0;
    for (int i = 0; i < per; ++i) {
        int idx = base + i;
        if (idx < N_NODES) s += cnt[idx];
    }
    part[t] = s;
    __syncthreads();
    for (int off = 1; off < 1024; off <<= 1) {
        int v = (t >= off) ? part[t - off] : 0;
        __syncthreads();
        part[t] += v;
        __syncthreads();
    }
    int run = part[t] - s;                    // exclusive prefix
    for (int i = 0; i < per; ++i) {
        int idx = base + i;
        if (idx < N_NODES) {
            offs[idx] = run;
            cursor[idx] = run;
            run += cnt[idx];
        }
    }
    if (t == 1023) offs[N_NODES] = part[1023];
}

__global__ __launch_bounds__(256) void fill_kernel(const int* __restrict__ edst,
                                                   const float* __restrict__ elen,
                                                   int* __restrict__ cursor,
                                                   int* __restrict__ perm) {
    int e = blockIdx.x * 256 + threadIdx.x;
    if (e >= N_EDGES) return;
    if (elen[e] <= 5.0f) {
        int pos = atomicAdd(&cursor[edst[e]], 1);
        perm[pos] = e;
    }
}

// ---------------- edge MLP + per-wave segmented scatter ----------------
// 4 waves x 32 dst-sorted edges, fully wave-independent (NO barrier).
// launch_bounds(256,4): cap 128 VGPR so the scheduler prefetches the
// unrolled A-fragment / xn loads across MFMA chains.
__global__ __launch_bounds__(256, 4) void edge_seg_kernel(
    const float* __restrict__ xn,
    const int* __restrict__ esrc, const int* __restrict__ edst,
    const float* __restrict__ rbf, const float* __restrict__ elen,
    const int* __restrict__ perm, const int* __restrict__ nlive_p,
    const unsigned short* __restrict__ wp_eg1, const unsigned short* __restrict__ wp_w1,
    const unsigned short* __restrict__ wp_w2,  const unsigned short* __restrict__ wp_w3,
    const float* __restrict__ eg_b1, const float* __restrict__ eg_w2,
    const float* __restrict__ eg_b2,
    const float* __restrict__ wm_b1, const float* __restrict__ wm_b2,
    const float* __restrict__ wm_b3,
    float* __restrict__ agg, float* __restrict__ nrm)
{
    __shared__ unsigned short act[4][32 * 136];
    __shared__ float ew_s[128];
    __shared__ int   dst_s[128];

    const int nlive = nlive_p[0];
    if (blockIdx.x * 128 >= nlive) return;

    const int tid  = threadIdx.x;
    const int w    = tid >> 6;
    const int lane = tid & 63;
    const int er   = lane & 15;
    const int kq   = lane >> 4;

    const int g0 = blockIdx.x * 128 + w * 32 + er;
    const int g1 = g0 + 16;
    const bool v0 = g0 < nlive, v1 = g1 < nlive;
    const int e0 = perm[v0 ? g0 : nlive - 1];
    const int e1 = perm[v1 ? g1 : nlive - 1];

    // rbf B-frags (8 consecutive k per lane, fp32 -> bf16 via cvt_pk)
    const float4* rp = (const float4*)(rbf + (size_t)e0 * RR + kq * 8);
    bf16x8 bfr0 = frag8(rp[0], rp[1]);
    const float4* rq = (const float4*)(rbf + (size_t)e1 * RR + kq * 8);
    bf16x8 bfr1 = frag8(rq[0], rq[1]);

    const int src0 = esrc[e0], dst0 = edst[e0];
    const int src1 = esrc[e1], dst1 = edst[e1];
    const float len0 = elen[e0], len1 = elen[e1];
    const float cut0 = v0 ? 0.5f * (__cosf(PI_F * len0 * 0.2f) + 1.0f) : 0.0f;
    const float cut1 = v1 ? 0.5f * (__cosf(PI_F * len1 * 0.2f) + 1.0f) : 0.0f;

    unsigned short* buf = &act[w][0];

    // ---- gate + L1 fused (16 independent MFMAs per t across both branches) --
    float pd0 = 0.0f, pd1 = 0.0f;
    #pragma unroll
    for (int t = 0; t < 8; ++t) {
        bf16x8 ag = *(const bf16x8*)(wp_eg1 + ((size_t)t * 64 + lane) * 8);
        bf16x8 a1 = *(const bf16x8*)(wp_w1  + ((size_t)t * 64 + lane) * 8);
        f32x4 z = {0.f, 0.f, 0.f, 0.f};
        f32x4 cg0 = __builtin_amdgcn_mfma_f32_16x16x32_bf16(ag, bfr0, z, 0, 0, 0);
        f32x4 cg1 = __builtin_amdgcn_mfma_f32_16x16x32_bf16(ag, bfr1, z, 0, 0, 0);
        f32x4 c10 = __builtin_amdgcn_mfma_f32_16x16x32_bf16(a1, bfr0, z, 0, 0, 0);
        f32x4 c11 = __builtin_amdgcn_mfma_f32_16x16x32_bf16(a1, bfr1, z, 0, 0, 0);
        float4 gb = *(const float4*)(eg_b1 + t * 16 + kq * 4);
        float4 w2 = *(const float4*)(eg_w2 + t * 16 + kq * 4);
        pd0 += silu_f(cg0[0]+gb.x)*w2.x + silu_f(cg0[1]+gb.y)*w2.y
             + silu_f(cg0[2]+gb.z)*w2.z + silu_f(cg0[3]+gb.w)*w2.w;
        pd1 += silu_f(cg1[0]+gb.x)*w2.x + silu_f(cg1[1]+gb.y)*w2.y
             + silu_f(cg1[2]+gb.z)*w2.z + silu_f(cg1[3]+gb.w)*w2.w;
        float4 b1 = *(const float4*)(wm_b1 + t * 16 + kq * 4);
        *(uint2*)(buf + er * 136 + t * 16 + kq * 4) =
            make_uint2(pk2(silu_f(c10[0]+b1.x), silu_f(c10[1]+b1.y)),
                       pk2(silu_f(c10[2]+b1.z), silu_f(c10[3]+b1.w)));
        *(uint2*)(buf + (16 + er) * 136 + t * 16 + kq * 4) =
            make_uint2(pk2(silu_f(c11[0]+b1.x), silu_f(c11[1]+b1.y)),
                       pk2(silu_f(c11[2]+b1.z), silu_f(c11[3]+b1.w)));
    }
    pd0 += __shfl_xor(pd0, 16); pd0 += __shfl_xor(pd0, 32);
    pd1 += __shfl_xor(pd1, 16); pd1 += __shfl_xor(pd1, 32);
    const float eb2 = eg_b2[0];
    const float ew0 = cut0 * sigmoid_f(pd0 + eb2);
    const float ew1 = cut1 * sigmoid_f(pd1 + eb2);
    if (lane < 16) {
        ew_s[w * 32 + er] = ew0;       dst_s[w * 32 + er] = dst0;
        ew_s[w * 32 + 16 + er] = ew1;  dst_s[w * 32 + 16 + er] = dst1;
    }

    // ---- L2: read frags to regs, then overwrite buf in place ----
    bf16x8 h0[4], h1[4];
    #pragma unroll
    for (int s = 0; s < 4; ++s) {
        h0[s] = *(const bf16x8*)(buf + er * 136 + s * 32 + kq * 8);
        h1[s] = *(const bf16x8*)(buf + (16 + er) * 136 + s * 32 + kq * 8);
    }
    #pragma unroll
    for (int t = 0; t < 8; ++t) {
        f32x4 c0 = {0.f, 0.f, 0.f, 0.f};
        f32x4 c1 = {0.f, 0.f, 0.f, 0.f};
        #pragma unroll
        for (int s = 0; s < 4; ++s) {
            bf16x8 af = *(const bf16x8*)(wp_w2 + (((size_t)s * 8 + t) * 64 + lane) * 8);
            c0 = __builtin_amdgcn_mfma_f32_16x16x32_bf16(af, h0[s], c0, 0, 0, 0);
            c1 = __builtin_amdgcn_mfma_f32_16x16x32_bf16(af, h1[s], c1, 0, 0, 0);
        }
        float4 b2 = *(const float4*)(wm_b2 + t * 16 + kq * 4);
        *(uint2*)(buf + er * 136 + t * 16 + kq * 4) =
            make_uint2(pk2(silu_f(c0[0]+b2.x), silu_f(c0[1]+b2.y)),
                       pk2(silu_f(c0[2]+b2.z), silu_f(c0[3]+b2.w)));
        *(uint2*)(buf + (16 + er) * 136 + t * 16 + kq * 4) =
            make_uint2(pk2(silu_f(c1[0]+b2.x), silu_f(c1[1]+b2.y)),
                       pk2(silu_f(c1[2]+b2.z), silu_f(c1[3]+b2.w)));
    }

    // ---- L3 + gather + bf16 message staging (in place) ----
    #pragma unroll
    for (int s = 0; s < 4; ++s) {
        h0[s] = *(const bf16x8*)(buf + er * 136 + s * 32 + kq * 8);
        h1[s] = *(const bf16x8*)(buf + (16 + er) * 136 + s * 32 + kq * 8);
    }
    const float* xr0 = xn + (size_t)src0 * DD;
    const float* xr1 = xn + (size_t)src1 * DD;
    #pragma unroll
    for (int t = 0; t < 8; ++t) {
        f32x4 c0 = {0.f, 0.f, 0.f, 0.f};
        f32x4 c1 = {0.f, 0.f, 0.f, 0.f};
        #pragma unroll
        for (int s = 0; s < 4; ++s) {
            bf16x8 af = *(const bf16x8*)(wp_w3 + (((size_t)s * 8 + t) * 64 + lane) * 8);
            c0 = __builtin_amdgcn_mfma_f32_16x16x32_bf16(af, h0[s], c0, 0, 0, 0);
            c1 = __builtin_amdgcn_mfma_f32_16x16x32_bf16(af, h1[s], c1, 0, 0, 0);
        }
        float4 b3 = *(const float4*)(wm_b3 + t * 16 + kq * 4);
        float4 xv0 = *(const float4*)(xr0 + t * 16 + kq * 4);
        float4 xv1 = *(const float4*)(xr1 + t * 16 + kq * 4);
        *(uint2*)(buf + er * 136 + t * 16 + kq * 4) =
            make_uint2(pk2((c0[0]+b3.x)*xv0.x*ew0, (c0[1]+b3.y)*xv0.y*ew0),
                       pk2((c0[2]+b3.z)*xv0.z*ew0, (c0[3]+b3.w)*xv0.w*ew0));
        *(uint2*)(buf + (16 + er) * 136 + t * 16 + kq * 4) =
            make_uint2(pk2((c1[0]+b3.x)*xv1.x*ew1, (c1[1]+b3.y)*xv1.y*ew1),
                       pk2((c1[2]+b3.z)*xv1.z*ew1, (c1[3]+b3.w)*xv1.w*ew1));
    }

    // ---- per-wave segmented reduce over this wave's 32 dst-sorted rows ----
    // lane handles f = 2*lane, 2*lane+1 (one ds_read_b32 per row)
    {
        const int rb = w * 32;
        float run0 = 0.0f, run1 = 0.0f, ewrun = 0.0f;
        int cur = dst_s[rb];
        #pragma unroll 8
        for (int i = 0; i < 32; ++i) {
            const int d = dst_s[rb + i];
            if (d != cur) {
                atomicAdd(&agg[(size_t)cur * DD + 2 * lane], run0);
                atomicAdd(&agg[(size_t)cur * DD + 2 * lane + 1], run1);
                if (lane == 0) atomicAdd(&nrm[cur], ewrun);
                run0 = 0.0f; run1 = 0.0f; ewrun = 0.0f; cur = d;
            }
            unsigned pv = *(const unsigned*)(buf + i * 136 + 2 * lane);
            run0 += __uint_as_float(pv << 16);
            run1 += __uint_as_float(pv & 0xffff0000u);
            ewrun += ew_s[rb + i];
        }
        atomicAdd(&agg[(size_t)cur * DD + 2 * lane], run0);
        atomicAdd(&agg[(size_t)cur * DD + 2 * lane + 1], run1);
        if (lane == 0) atomicAdd(&nrm[cur], ewrun);
    }
}

// ---------------- Node finalize (MFMA): 64 nodes/block, 16 per wave ----------
__global__ __launch_bounds__(256) void node_kernel(
    const float* __restrict__ x, const float* __restrict__ xn,
    const float* __restrict__ agg, const float* __restrict__ nrm,
    const unsigned short* __restrict__ wp_mm1, const unsigned short* __restrict__ wp_mm2,
    const unsigned short* __restrict__ wp_sl,  const unsigned short* __restrict__ wp_ul,
    const float* __restrict__ mm_b1, const float* __restrict__ mm_b2,
    const float* __restrict__ sl_b, const float* __restrict__ ul_b,
    const float* __restrict__ res_scale, float* __restrict__ out)
{
    __shared__ unsigned short act[4][16 * 136];

    const int tid  = threadIdx.x;
    const int w    = tid >> 6;
    const int lane = tid & 63;
    const int er   = lane & 15;
    const int kq   = lane >> 4;

    const int n  = blockIdx.x * 64 + w * 16 + er;
    const bool valid = n < N_NODES;
    const int nc = valid ? n : N_NODES - 1;

    const float rs = __builtin_amdgcn_rcpf(fmaxf(nrm[nc], 1e-8f));
    const float rscl = res_scale[0];

    bf16x8 ba[4];
    #pragma unroll
    for (int s = 0; s < 4; ++s) {
        const float4* ap = (const float4*)(agg + (size_t)nc * DD + s * 32 + kq * 8);
        float4 a = ap[0], b = ap[1];
        a.x *= rs; a.y *= rs; a.z *= rs; a.w *= rs;
        b.x *= rs; b.y *= rs; b.z *= rs; b.w *= rs;
        ba[s] = frag8(a, b);
    }

    unsigned short* buf = &act[w][0];

    // mm1
    #pragma unroll
    for (int t = 0; t < 8; ++t) {
        f32x4 c = {0.f, 0.f, 0.f, 0.f};
        #pragma unroll
        for (int s = 0; s < 4; ++s) {
            bf16x8 af = *(const bf16x8*)(wp_mm1 + (((size_t)s * 8 + t) * 64 + lane) * 8);
            c = __builtin_amdgcn_mfma_f32_16x16x32_bf16(af, ba[s], c, 0, 0, 0);
        }
        float4 b1 = *(const float4*)(mm_b1 + t * 16 + kq * 4);
        *(uint2*)(buf + er * 136 + t * 16 + kq * 4) =
            make_uint2(pk2(silu_f(c[0]+b1.x), silu_f(c[1]+b1.y)),
                       pk2(silu_f(c[2]+b1.z), silu_f(c[3]+b1.w)));
    }

    // mm2
    bf16x8 bh[4];
    #pragma unroll
    for (int s = 0; s < 4; ++s)
        bh[s] = *(const bf16x8*)(buf + er * 136 + s * 32 + kq * 8);
    #pragma unroll
    for (int t = 0; t < 8; ++t) {
        f32x4 c = {0.f, 0.f, 0.f, 0.f};
        #pragma unroll
        for (int s = 0; s < 4; ++s) {
            bf16x8 af = *(const bf16x8*)(wp_mm2 + (((size_t)s * 8 + t) * 64 + lane) * 8);
            c = __builtin_amdgcn_mfma_f32_16x16x32_bf16(af, bh[s], c, 0, 0, 0);
        }
        float4 b2 = *(const float4*)(mm_b2 + t * 16 + kq * 4);
        *(uint2*)(buf + er * 136 + t * 16 + kq * 4) =
            make_uint2(pk2(c[0]+b2.x, c[1]+b2.y), pk2(c[2]+b2.z, c[3]+b2.w));
    }

    bf16x8 bg[4], bx[4];
    #pragma unroll
    for (int s = 0; s < 4; ++s) {
        bg[s] = *(const bf16x8*)(buf + er * 136 + s * 32 + kq * 8);
        const float4* xp = (const float4*)(xn + (size_t)nc * DD + s * 32 + kq * 8);
        bx[s] = frag8(xp[0], xp[1]);
    }

    #pragma unroll
    for (int t = 0; t < 8; ++t) {
        f32x4 c = {0.f, 0.f, 0.f, 0.f};
        #pragma unroll
        for (int s = 0; s < 4; ++s) {
            bf16x8 af = *(const bf16x8*)(wp_sl + (((size_t)s * 8 + t) * 64 + lane) * 8);
            c = __builtin_amdgcn_mfma_f32_16x16x32_bf16(af, bx[s], c, 0, 0, 0);
        }
        #pragma unroll
        for (int s = 0; s < 4; ++s) {
            bf16x8 af = *(const bf16x8*)(wp_ul + (((size_t)s * 8 + t) * 64 + lane) * 8);
            c = __builtin_amdgcn_mfma_f32_16x16x32_bf16(af, bg[s], c, 0, 0, 0);
        }
        if (valid) {
            float4 sb = *(const float4*)(sl_b + t * 16 + kq * 4);
            float4 ub = *(const float4*)(ul_b + t * 16 + kq * 4);
            float4 xv = *(const float4*)(x + (size_t)n * DD + t * 16 + kq * 4);
            float4 o;
            o.x = xv.x + rscl * (c[0] + sb.x + ub.x);
            o.y = xv.y + rscl * (c[1] + sb.y + ub.y);
            o.z = xv.z + rscl * (c[2] + sb.z + ub.z);
            o.w = xv.w + rscl * (c[3] + sb.w + ub.w);
            *(float4*)(out + (size_t)n * DD + t * 16 + kq * 4) = o;
        }
    }
}

extern "C" void kernel_launch(void* const* d_in, const int* in_sizes, int n_in,
                              void* d_out, int out_size, void* d_ws, size_t ws_size,
                              hipStream_t stream) {
    const float* x     = (const float*)d_in[0];
    const int*   esrc  = (const int*)d_in[1];
    const int*   edst  = (const int*)d_in[2];
    // d_in[3] = edge_sh (unused)
    const float* rbf   = (const float*)d_in[4];
    const float* elen  = (const float*)d_in[5];
    const float* ln_g  = (const float*)d_in[6];
    const float* ln_b  = (const float*)d_in[7];
    const float* wm_w1 = (const float*)d_in[8];
    const float* wm_b1 = (const float*)d_in[9];
    const float* wm_w2 = (const float*)d_in[10];
    const float* wm_b2 = (const float*)d_in[11];
    const float* wm_w3 = (const float*)d_in[12];
    const float* wm_b3 = (const float*)d_in[13];
    const float* eg_w1 = (const float*)d_in[14];
    const float* eg_b1 = (const float*)d_in[15];
    const float* eg_w2 = (const float*)d_in[16];
    const float* eg_b2 = (const float*)d_in[17];
    const float* mm_w1 = (const float*)d_in[18];
    const float* mm_b1 = (const float*)d_in[19];
    const float* mm_w2 = (const float*)d_in[20];
    const float* mm_b2 = (const float*)d_in[21];
    const float* sl_w  = (const float*)d_in[22];
    const float* sl_b  = (const float*)d_in[23];
    const float* ul_w  = (const float*)d_in[24];
    const float* ul_b  = (const float*)d_in[25];
    const float* rscl  = (const float*)d_in[26];

    float* xn  = (float*)d_ws;                                  // 2.56M f
    float* agg = xn + (size_t)N_NODES * DD;                     // 2.56M f
    float* nrm = agg + (size_t)N_NODES * DD;                    // 20000 f
    int*   cnt = (int*)(nrm + N_NODES);                         // 20000 i
    unsigned short* wp = (unsigned short*)(cnt + N_NODES);      // 106496 us
    unsigned short* wp_eg1 = wp;
    unsigned short* wp_w1  = wp_eg1 + 4096;
    unsigned short* wp_w2  = wp_w1 + 4096;
    unsigned short* wp_w3  = wp_w2 + 16384;
    unsigned short* wp_mm1 = wp_w3 + 16384;
    unsigned short* wp_mm2 = wp_mm1 + 16384;
    unsigned short* wp_sl  = wp_mm2 + 16384;
    unsigned short* wp_ul  = wp_sl + 16384;
    int* offs   = (int*)(wp_ul + 16384);
    int* cursor = offs + N_NODES + 1;
    int* perm   = cursor + N_NODES;

    // one memset covers agg | nrm | cnt (contiguous)
    hipMemsetAsync(agg, 0, (size_t)(N_NODES * DD + 2 * N_NODES) * sizeof(float), stream);
    prep_kernel<<<NPACK + NLN + NHIST, 256, 0, stream>>>(
        eg_w1, wm_w1, wm_w2, wm_w3, mm_w1, mm_w2, sl_w, ul_w, wp,
        x, ln_g, ln_b, xn, edst, elen, cnt);
    scan_kernel<<<1, 1024, 0, stream>>>(cnt, offs, cursor);
    fill_kernel<<<N_EDGES / 256, 256, 0, stream>>>(edst, elen, cursor, perm);
    edge_seg_kernel<<<N_EDGES / 128, 256, 0, stream>>>(xn, esrc, edst, rbf, elen,
        perm, offs + N_NODES,
        wp_eg1, wp_w1, wp_w2, wp_w3,
        eg_b1, eg_w2, eg_b2, wm_b1, wm_b2, wm_b3, agg, nrm);
    node_kernel<<<(N_NODES + 63) / 64, 256, 0, stream>>>(x, xn, agg, nrm,
        wp_mm1, wp_mm2, wp_sl, wp_ul,
        mm_b1, mm_b2, sl_b, ul_b, rscl, (float*)d_out);
}

// Round 8
// 228.153 us; speedup vs baseline: 4.9454x; 1.0651x over previous
//
#include <hip/hip_runtime.h>
#include <math.h>

#define N_NODES 20000
#define N_EDGES 640000
#define DD 128
#define RR 32
#define HH 128
#define PI_F 3.14159265358979323846f

// prep_kernel block ranges
#define NPACK 416      // 106496 packed weights / 256
#define NLN   5000     // 20000 nodes / 4 rows per block
#define NHIST 2500     // 640000 edges / 256

typedef short bf16x8 __attribute__((ext_vector_type(8)));
typedef float f32x4 __attribute__((ext_vector_type(4)));
typedef __bf16 bf16x2_t __attribute__((ext_vector_type(2)));

__device__ __forceinline__ float silu_f(float x) {
    return x * __builtin_amdgcn_rcpf(1.0f + __expf(-x));
}
__device__ __forceinline__ float sigmoid_f(float x) {
    return __builtin_amdgcn_rcpf(1.0f + __expf(-x));
}
__device__ __forceinline__ unsigned short f2bf(float x) {
    __bf16 h = (__bf16)x;
    return __builtin_bit_cast(unsigned short, h);
}
__device__ __forceinline__ unsigned pk2(float lo, float hi) {
    bf16x2_t v;
    v[0] = (__bf16)lo; v[1] = (__bf16)hi;
    return __builtin_bit_cast(unsigned, v);
}
__device__ __forceinline__ bf16x8 frag8(float4 a, float4 b) {
    union { unsigned u[4]; bf16x8 v; } r;
    r.u[0] = pk2(a.x, a.y); r.u[1] = pk2(a.z, a.w);
    r.u[2] = pk2(b.x, b.y); r.u[3] = pk2(b.z, b.w);
    return r.v;
}

// pack W[K][F] fp32 -> bf16 MFMA-A-fragment order:
// packed[((s*NT + t)*64 + l)*8 + j] = W[s*32 + (l>>4)*8 + j][t*16 + (l&15)]
__device__ __forceinline__ unsigned short pack_one(const float* __restrict__ src,
                                                   int o, int F) {
    int NT = F >> 4;
    int j = o & 7;
    int l = (o >> 3) & 63;
    int rest = o >> 9;
    int t = rest % NT;
    int s = rest / NT;
    int k = s * 32 + ((l >> 4) << 3) + j;
    int f = t * 16 + (l & 15);
    return f2bf(src[(size_t)k * F + f]);
}

// ---------------- prep: weight packs + LayerNorm + histogram in one launch ---
__global__ __launch_bounds__(256) void prep_kernel(
    const float* __restrict__ eg_w1, const float* __restrict__ wm_w1,
    const float* __restrict__ wm_w2, const float* __restrict__ wm_w3,
    const float* __restrict__ mm_w1, const float* __restrict__ mm_w2,
    const float* __restrict__ sl_w,  const float* __restrict__ ul_w,
    unsigned short* __restrict__ wp,
    const float* __restrict__ x, const float* __restrict__ g,
    const float* __restrict__ b, float* __restrict__ xn,
    const int* __restrict__ edst, const float* __restrict__ elen,
    int* __restrict__ cnt)
{
    const int blk = blockIdx.x;
    if (blk < NPACK) {
        int o = blk * 256 + threadIdx.x;
        unsigned short v;
        if      (o < 4096)   v = pack_one(eg_w1, o,          HH);
        else if (o < 8192)   v = pack_one(wm_w1, o - 4096,   HH);
        else if (o < 24576)  v = pack_one(wm_w2, o - 8192,   HH);
        else if (o < 40960)  v = pack_one(wm_w3, o - 24576,  DD);
        else if (o < 57344)  v = pack_one(mm_w1, o - 40960,  HH);
        else if (o < 73728)  v = pack_one(mm_w2, o - 57344,  DD);
        else if (o < 90112)  v = pack_one(sl_w,  o - 73728,  DD);
        else                 v = pack_one(ul_w,  o - 90112,  DD);
        wp[o] = v;
    } else if (blk < NPACK + NLN) {
        int wid = ((blk - NPACK) * 256 + threadIdx.x) >> 6;
        int lane = threadIdx.x & 63;
        if (wid >= N_NODES) return;
        const float* row = x + (size_t)wid * DD;
        float v0 = row[lane], v1 = row[lane + 64];
        float s = v0 + v1, sq = v0 * v0 + v1 * v1;
        #pragma unroll
        for (int o = 32; o > 0; o >>= 1) { s += __shfl_xor(s, o); sq += __shfl_xor(sq, o); }
        float mu = s * (1.0f / 128.0f);
        float var = sq * (1.0f / 128.0f) - mu * mu;
        float inv = rsqrtf(var + 1e-5f);
        float* orow = xn + (size_t)wid * DD;
        orow[lane]      = (v0 - mu) * inv * g[lane]      + b[lane];
        orow[lane + 64] = (v1 - mu) * inv * g[lane + 64] + b[lane + 64];
    } else {
        int e = (blk - NPACK - NLN) * 256 + threadIdx.x;
        if (e < N_EDGES && elen[e] <= 5.0f) atomicAdd(&cnt[edst[e]], 1);
    }
}

// ---------------- parallel scan over node counts ----------------
__global__ __launch_bounds__(1024) void scan_kernel(const int* __restrict__ cnt,
                                                    int* __restrict__ offs,
                                                    int* __restrict__ cursor) {
    __shared__ int part[1024];
    const int t = threadIdx.x;
    const int per = 20;
    const int base = t * per;
    int s = 0;
    for (int i = 0; i < per; ++i) {
        int idx = base + i;
        if (idx < N_NODES) s += cnt[idx];
    }
    part[t] = s;
    __syncthreads();
    for (int off = 1; off < 1024; off <<= 1) {
        int v = (t >= off) ? part[t - off] : 0;
        __syncthreads();
        part[t] += v;
        __syncthreads();
    }
    int run = part[t] - s;
    for (int i = 0; i < per; ++i) {
        int idx = base + i;
        if (idx < N_NODES) {
            offs[idx] = run;
            cursor[idx] = run;
            run += cnt[idx];
        }
    }
    if (t == 1023) offs[N_NODES] = part[1023];
}

__global__ __launch_bounds__(256) void fill_kernel(const int* __restrict__ edst,
                                                   const float* __restrict__ elen,
                                                   int* __restrict__ cursor,
                                                   int* __restrict__ perm) {
    int e = blockIdx.x * 256 + threadIdx.x;
    if (e >= N_EDGES) return;
    if (elen[e] <= 5.0f) {
        int pos = atomicAdd(&cursor[edst[e]], 1);
        perm[pos] = e;
    }
}

// ---------------- edge MLP + per-wave segmented scatter ----------------
// 4 waves x 64 dst-sorted edges (4 MFMA B-groups/wave -> each A-fragment
// load feeds 4 MFMAs). Explicit double-buffered fragment regs force loads
// in flight across the MFMA chain. Wave-independent, no barrier.
__global__ __launch_bounds__(256, 2) void edge_seg_kernel(
    const float* __restrict__ xn,
    const int* __restrict__ esrc, const int* __restrict__ edst,
    const float* __restrict__ rbf, const float* __restrict__ elen,
    const int* __restrict__ perm, const int* __restrict__ nlive_p,
    const unsigned short* __restrict__ wp_eg1, const unsigned short* __restrict__ wp_w1,
    const unsigned short* __restrict__ wp_w2,  const unsigned short* __restrict__ wp_w3,
    const float* __restrict__ eg_b1, const float* __restrict__ eg_w2,
    const float* __restrict__ eg_b2,
    const float* __restrict__ wm_b1, const float* __restrict__ wm_b2,
    const float* __restrict__ wm_b3,
    float* __restrict__ agg, float* __restrict__ nrm)
{
    __shared__ unsigned short act[4][64 * 136];
    __shared__ float ew_s[256];
    __shared__ int   dst_s[256];

    const int nlive = nlive_p[0];
    if (blockIdx.x * 256 >= nlive) return;

    const int tid  = threadIdx.x;
    const int w    = tid >> 6;
    const int lane = tid & 63;
    const int er   = lane & 15;
    const int kq   = lane >> 4;

    const int gbase = blockIdx.x * 256 + w * 64 + er;
    int eidx[4]; bool val[4];
    #pragma unroll
    for (int g = 0; g < 4; ++g) {
        int gi = gbase + g * 16;
        val[g] = gi < nlive;
        eidx[g] = perm[val[g] ? gi : nlive - 1];
    }

    bf16x8 bfr[4];
    int srcv[4];
    float ew[4];
    {
        float cut[4]; int dstv[4];
        #pragma unroll
        for (int g = 0; g < 4; ++g) {
            const float4* rp = (const float4*)(rbf + (size_t)eidx[g] * RR + kq * 8);
            bfr[g] = frag8(rp[0], rp[1]);
            srcv[g] = esrc[eidx[g]];
            dstv[g] = edst[eidx[g]];
            float len = elen[eidx[g]];
            cut[g] = val[g] ? 0.5f * (__cosf(PI_F * len * 0.2f) + 1.0f) : 0.0f;
        }

        unsigned short* buf = &act[w][0];

        // ---- gate + L1 fused, double-buffered A-frags ----
        float pd[4] = {0.f, 0.f, 0.f, 0.f};
        bf16x8 agc = *(const bf16x8*)(wp_eg1 + (size_t)lane * 8);
        bf16x8 a1c = *(const bf16x8*)(wp_w1  + (size_t)lane * 8);
        #pragma unroll
        for (int t = 0; t < 8; ++t) {
            const int tn = (t + 1) & 7;
            bf16x8 agn = *(const bf16x8*)(wp_eg1 + ((size_t)tn * 64 + lane) * 8);
            bf16x8 a1n = *(const bf16x8*)(wp_w1  + ((size_t)tn * 64 + lane) * 8);
            const f32x4 z = {0.f, 0.f, 0.f, 0.f};
            float4 gb = *(const float4*)(eg_b1 + t * 16 + kq * 4);
            float4 w2 = *(const float4*)(eg_w2 + t * 16 + kq * 4);
            float4 b1 = *(const float4*)(wm_b1 + t * 16 + kq * 4);
            #pragma unroll
            for (int g = 0; g < 4; ++g) {
                f32x4 cg = __builtin_amdgcn_mfma_f32_16x16x32_bf16(agc, bfr[g], z, 0, 0, 0);
                f32x4 c1 = __builtin_amdgcn_mfma_f32_16x16x32_bf16(a1c, bfr[g], z, 0, 0, 0);
                pd[g] += silu_f(cg[0]+gb.x)*w2.x + silu_f(cg[1]+gb.y)*w2.y
                       + silu_f(cg[2]+gb.z)*w2.z + silu_f(cg[3]+gb.w)*w2.w;
                *(uint2*)(buf + (g * 16 + er) * 136 + t * 16 + kq * 4) =
                    make_uint2(pk2(silu_f(c1[0]+b1.x), silu_f(c1[1]+b1.y)),
                               pk2(silu_f(c1[2]+b1.z), silu_f(c1[3]+b1.w)));
            }
            agc = agn; a1c = a1n;
        }
        const float eb2 = eg_b2[0];
        #pragma unroll
        for (int g = 0; g < 4; ++g) {
            pd[g] += __shfl_xor(pd[g], 16);
            pd[g] += __shfl_xor(pd[g], 32);
            ew[g] = cut[g] * sigmoid_f(pd[g] + eb2);
        }
        if (lane < 16) {
            #pragma unroll
            for (int g = 0; g < 4; ++g) {
                ew_s[w * 64 + g * 16 + er] = ew[g];
                dst_s[w * 64 + g * 16 + er] = dstv[g];
            }
        }
    }

    unsigned short* buf = &act[w][0];

    // ---- L2: read all h frags to regs, then overwrite buf in place ----
    {
        bf16x8 h[4][4];
        #pragma unroll
        for (int g = 0; g < 4; ++g)
            #pragma unroll
            for (int s = 0; s < 4; ++s)
                h[g][s] = *(const bf16x8*)(buf + (g * 16 + er) * 136 + s * 32 + kq * 8);

        bf16x8 afc[4];
        #pragma unroll
        for (int s = 0; s < 4; ++s)
            afc[s] = *(const bf16x8*)(wp_w2 + (((size_t)s * 8 + 0) * 64 + lane) * 8);
        #pragma unroll
        for (int t = 0; t < 8; ++t) {
            const int tn = (t + 1) & 7;
            bf16x8 afn[4];
            #pragma unroll
            for (int s = 0; s < 4; ++s)
                afn[s] = *(const bf16x8*)(wp_w2 + (((size_t)s * 8 + tn) * 64 + lane) * 8);
            float4 b2 = *(const float4*)(wm_b2 + t * 16 + kq * 4);
            #pragma unroll
            for (int g = 0; g < 4; ++g) {
                f32x4 c = {0.f, 0.f, 0.f, 0.f};
                #pragma unroll
                for (int s = 0; s < 4; ++s)
                    c = __builtin_amdgcn_mfma_f32_16x16x32_bf16(afc[s], h[g][s], c, 0, 0, 0);
                *(uint2*)(buf + (g * 16 + er) * 136 + t * 16 + kq * 4) =
                    make_uint2(pk2(silu_f(c[0]+b2.x), silu_f(c[1]+b2.y)),
                               pk2(silu_f(c[2]+b2.z), silu_f(c[3]+b2.w)));
            }
            #pragma unroll
            for (int s = 0; s < 4; ++s) afc[s] = afn[s];
        }
    }

    // ---- L3 + gather + bf16 message staging (in place) ----
    {
        bf16x8 h[4][4];
        #pragma unroll
        for (int g = 0; g < 4; ++g)
            #pragma unroll
            for (int s = 0; s < 4; ++s)
                h[g][s] = *(const bf16x8*)(buf + (g * 16 + er) * 136 + s * 32 + kq * 8);

        bf16x8 afc[4];
        #pragma unroll
        for (int s = 0; s < 4; ++s)
            afc[s] = *(const bf16x8*)(wp_w3 + (((size_t)s * 8 + 0) * 64 + lane) * 8);
        #pragma unroll
        for (int t = 0; t < 8; ++t) {
            const int tn = (t + 1) & 7;
            bf16x8 afn[4];
            #pragma unroll
            for (int s = 0; s < 4; ++s)
                afn[s] = *(const bf16x8*)(wp_w3 + (((size_t)s * 8 + tn) * 64 + lane) * 8);
            float4 b3 = *(const float4*)(wm_b3 + t * 16 + kq * 4);
            #pragma unroll
            for (int g = 0; g < 4; ++g) {
                f32x4 c = {0.f, 0.f, 0.f, 0.f};
                #pragma unroll
                for (int s = 0; s < 4; ++s)
                    c = __builtin_amdgcn_mfma_f32_16x16x32_bf16(afc[s], h[g][s], c, 0, 0, 0);
                float4 xv = *(const float4*)(xn + (size_t)srcv[g] * DD + t * 16 + kq * 4);
                *(uint2*)(buf + (g * 16 + er) * 136 + t * 16 + kq * 4) =
                    make_uint2(pk2((c[0]+b3.x)*xv.x*ew[g], (c[1]+b3.y)*xv.y*ew[g]),
                               pk2((c[2]+b3.z)*xv.z*ew[g], (c[3]+b3.w)*xv.w*ew[g]));
            }
            #pragma unroll
            for (int s = 0; s < 4; ++s) afc[s] = afn[s];
        }
    }

    // ---- per-wave segmented reduce over this wave's 64 dst-sorted rows ----
    {
        const int rb = w * 64;
        float run0 = 0.0f, run1 = 0.0f, ewrun = 0.0f;
        int cur = dst_s[rb];
        #pragma unroll 8
        for (int i = 0; i < 64; ++i) {
            const int d = dst_s[rb + i];
            if (d != cur) {
                atomicAdd(&agg[(size_t)cur * DD + 2 * lane], run0);
                atomicAdd(&agg[(size_t)cur * DD + 2 * lane + 1], run1);
                if (lane == 0) atomicAdd(&nrm[cur], ewrun);
                run0 = 0.0f; run1 = 0.0f; ewrun = 0.0f; cur = d;
            }
            unsigned pv = *(const unsigned*)(buf + i * 136 + 2 * lane);
            run0 += __uint_as_float(pv << 16);
            run1 += __uint_as_float(pv & 0xffff0000u);
            ewrun += ew_s[rb + i];
        }
        atomicAdd(&agg[(size_t)cur * DD + 2 * lane], run0);
        atomicAdd(&agg[(size_t)cur * DD + 2 * lane + 1], run1);
        if (lane == 0) atomicAdd(&nrm[cur], ewrun);
    }
}

// ---------------- Node finalize (MFMA): 128 nodes/block, 32 per wave --------
__global__ __launch_bounds__(256) void node_kernel(
    const float* __restrict__ x, const float* __restrict__ xn,
    const float* __restrict__ agg, const float* __restrict__ nrm,
    const unsigned short* __restrict__ wp_mm1, const unsigned short* __restrict__ wp_mm2,
    const unsigned short* __restrict__ wp_sl,  const unsigned short* __restrict__ wp_ul,
    const float* __restrict__ mm_b1, const float* __restrict__ mm_b2,
    const float* __restrict__ sl_b, const float* __restrict__ ul_b,
    const float* __restrict__ res_scale, float* __restrict__ out)
{
    __shared__ unsigned short act[4][32 * 136];

    const int tid  = threadIdx.x;
    const int w    = tid >> 6;
    const int lane = tid & 63;
    const int er   = lane & 15;
    const int kq   = lane >> 4;

    const int n0 = blockIdx.x * 128 + w * 32 + er;
    const int n1 = n0 + 16;
    const bool val0 = n0 < N_NODES, val1 = n1 < N_NODES;
    const int nc0 = val0 ? n0 : N_NODES - 1;
    const int nc1 = val1 ? n1 : N_NODES - 1;

    const float rs0 = __builtin_amdgcn_rcpf(fmaxf(nrm[nc0], 1e-8f));
    const float rs1 = __builtin_amdgcn_rcpf(fmaxf(nrm[nc1], 1e-8f));
    const float rscl = res_scale[0];

    bf16x8 ba0[4], ba1[4];
    #pragma unroll
    for (int s = 0; s < 4; ++s) {
        const float4* ap = (const float4*)(agg + (size_t)nc0 * DD + s * 32 + kq * 8);
        float4 a = ap[0], b = ap[1];
        a.x*=rs0; a.y*=rs0; a.z*=rs0; a.w*=rs0; b.x*=rs0; b.y*=rs0; b.z*=rs0; b.w*=rs0;
        ba0[s] = frag8(a, b);
        const float4* aq = (const float4*)(agg + (size_t)nc1 * DD + s * 32 + kq * 8);
        float4 c = aq[0], d = aq[1];
        c.x*=rs1; c.y*=rs1; c.z*=rs1; c.w*=rs1; d.x*=rs1; d.y*=rs1; d.z*=rs1; d.w*=rs1;
        ba1[s] = frag8(c, d);
    }

    unsigned short* buf = &act[w][0];

    // mm1
    #pragma unroll
    for (int t = 0; t < 8; ++t) {
        f32x4 c0 = {0.f,0.f,0.f,0.f}, c1 = {0.f,0.f,0.f,0.f};
        #pragma unroll
        for (int s = 0; s < 4; ++s) {
            bf16x8 af = *(const bf16x8*)(wp_mm1 + (((size_t)s * 8 + t) * 64 + lane) * 8);
            c0 = __builtin_amdgcn_mfma_f32_16x16x32_bf16(af, ba0[s], c0, 0, 0, 0);
            c1 = __builtin_amdgcn_mfma_f32_16x16x32_bf16(af, ba1[s], c1, 0, 0, 0);
        }
        float4 b1 = *(const float4*)(mm_b1 + t * 16 + kq * 4);
        *(uint2*)(buf + er * 136 + t * 16 + kq * 4) =
            make_uint2(pk2(silu_f(c0[0]+b1.x), silu_f(c0[1]+b1.y)),
                       pk2(silu_f(c0[2]+b1.z), silu_f(c0[3]+b1.w)));
        *(uint2*)(buf + (16 + er) * 136 + t * 16 + kq * 4) =
            make_uint2(pk2(silu_f(c1[0]+b1.x), silu_f(c1[1]+b1.y)),
                       pk2(silu_f(c1[2]+b1.z), silu_f(c1[3]+b1.w)));
    }

    // mm2
    bf16x8 bh0[4], bh1[4];
    #pragma unroll
    for (int s = 0; s < 4; ++s) {
        bh0[s] = *(const bf16x8*)(buf + er * 136 + s * 32 + kq * 8);
        bh1[s] = *(const bf16x8*)(buf + (16 + er) * 136 + s * 32 + kq * 8);
    }
    #pragma unroll
    for (int t = 0; t < 8; ++t) {
        f32x4 c0 = {0.f,0.f,0.f,0.f}, c1 = {0.f,0.f,0.f,0.f};
        #pragma unroll
        for (int s = 0; s < 4; ++s) {
            bf16x8 af = *(const bf16x8*)(wp_mm2 + (((size_t)s * 8 + t) * 64 + lane) * 8);
            c0 = __builtin_amdgcn_mfma_f32_16x16x32_bf16(af, bh0[s], c0, 0, 0, 0);
            c1 = __builtin_amdgcn_mfma_f32_16x16x32_bf16(af, bh1[s], c1, 0, 0, 0);
        }
        float4 b2 = *(const float4*)(mm_b2 + t * 16 + kq * 4);
        *(uint2*)(buf + er * 136 + t * 16 + kq * 4) =
            make_uint2(pk2(c0[0]+b2.x, c0[1]+b2.y), pk2(c0[2]+b2.z, c0[3]+b2.w));
        *(uint2*)(buf + (16 + er) * 136 + t * 16 + kq * 4) =
            make_uint2(pk2(c1[0]+b2.x, c1[1]+b2.y), pk2(c1[2]+b2.z, c1[3]+b2.w));
    }

    bf16x8 bg0[4], bg1[4], bx0[4], bx1[4];
    #pragma unroll
    for (int s = 0; s < 4; ++s) {
        bg0[s] = *(const bf16x8*)(buf + er * 136 + s * 32 + kq * 8);
        bg1[s] = *(const bf16x8*)(buf + (16 + er) * 136 + s * 32 + kq * 8);
        const float4* xp = (const float4*)(xn + (size_t)nc0 * DD + s * 32 + kq * 8);
        bx0[s] = frag8(xp[0], xp[1]);
        const float4* xq = (const float4*)(xn + (size_t)nc1 * DD + s * 32 + kq * 8);
        bx1[s] = frag8(xq[0], xq[1]);
    }

    #pragma unroll
    for (int t = 0; t < 8; ++t) {
        f32x4 c0 = {0.f,0.f,0.f,0.f}, c1 = {0.f,0.f,0.f,0.f};
        #pragma unroll
        for (int s = 0; s < 4; ++s) {
            bf16x8 af = *(const bf16x8*)(wp_sl + (((size_t)s * 8 + t) * 64 + lane) * 8);
            c0 = __builtin_amdgcn_mfma_f32_16x16x32_bf16(af, bx0[s], c0, 0, 0, 0);
            c1 = __builtin_amdgcn_mfma_f32_16x16x32_bf16(af, bx1[s], c1, 0, 0, 0);
        }
        #pragma unroll
        for (int s = 0; s < 4; ++s) {
            bf16x8 af = *(const bf16x8*)(wp_ul + (((size_t)s * 8 + t) * 64 + lane) * 8);
            c0 = __builtin_amdgcn_mfma_f32_16x16x32_bf16(af, bg0[s], c0, 0, 0, 0);
            c1 = __builtin_amdgcn_mfma_f32_16x16x32_bf16(af, bg1[s], c1, 0, 0, 0);
        }
        float4 sb = *(const float4*)(sl_b + t * 16 + kq * 4);
        float4 ub = *(const float4*)(ul_b + t * 16 + kq * 4);
        if (val0) {
            float4 xv = *(const float4*)(x + (size_t)n0 * DD + t * 16 + kq * 4);
            float4 o;
            o.x = xv.x + rscl * (c0[0] + sb.x + ub.x);
            o.y = xv.y + rscl * (c0[1] + sb.y + ub.y);
            o.z = xv.z + rscl * (c0[2] + sb.z + ub.z);
            o.w = xv.w + rscl * (c0[3] + sb.w + ub.w);
            *(float4*)(out + (size_t)n0 * DD + t * 16 + kq * 4) = o;
        }
        if (val1) {
            float4 xv = *(const float4*)(x + (size_t)n1 * DD + t * 16 + kq * 4);
            float4 o;
            o.x = xv.x + rscl * (c1[0] + sb.x + ub.x);
            o.y = xv.y + rscl * (c1[1] + sb.y + ub.y);
            o.z = xv.z + rscl * (c1[2] + sb.z + ub.z);
            o.w = xv.w + rscl * (c1[3] + sb.w + ub.w);
            *(float4*)(out + (size_t)n1 * DD + t * 16 + kq * 4) = o;
        }
    }
}

extern "C" void kernel_launch(void* const* d_in, const int* in_sizes, int n_in,
                              void* d_out, int out_size, void* d_ws, size_t ws_size,
                              hipStream_t stream) {
    const float* x     = (const float*)d_in[0];
    const int*   esrc  = (const int*)d_in[1];
    const int*   edst  = (const int*)d_in[2];
    // d_in[3] = edge_sh (unused)
    const float* rbf   = (const float*)d_in[4];
    const float* elen  = (const float*)d_in[5];
    const float* ln_g  = (const float*)d_in[6];
    const float* ln_b  = (const float*)d_in[7];
    const float* wm_w1 = (const float*)d_in[8];
    const float* wm_b1 = (const float*)d_in[9];
    const float* wm_w2 = (const float*)d_in[10];
    const float* wm_b2 = (const float*)d_in[11];
    const float* wm_w3 = (const float*)d_in[12];
    const float* wm_b3 = (const float*)d_in[13];
    const float* eg_w1 = (const float*)d_in[14];
    const float* eg_b1 = (const float*)d_in[15];
    const float* eg_w2 = (const float*)d_in[16];
    const float* eg_b2 = (const float*)d_in[17];
    const float* mm_w1 = (const float*)d_in[18];
    const float* mm_b1 = (const float*)d_in[19];
    const float* mm_w2 = (const float*)d_in[20];
    const float* mm_b2 = (const float*)d_in[21];
    const float* sl_w  = (const float*)d_in[22];
    const float* sl_b  = (const float*)d_in[23];
    const float* ul_w  = (const float*)d_in[24];
    const float* ul_b  = (const float*)d_in[25];
    const float* rscl  = (const float*)d_in[26];

    float* xn  = (float*)d_ws;
    float* agg = xn + (size_t)N_NODES * DD;
    float* nrm = agg + (size_t)N_NODES * DD;
    int*   cnt = (int*)(nrm + N_NODES);
    unsigned short* wp = (unsigned short*)(cnt + N_NODES);
    unsigned short* wp_eg1 = wp;
    unsigned short* wp_w1  = wp_eg1 + 4096;
    unsigned short* wp_w2  = wp_w1 + 4096;
    unsigned short* wp_w3  = wp_w2 + 16384;
    unsigned short* wp_mm1 = wp_w3 + 16384;
    unsigned short* wp_mm2 = wp_mm1 + 16384;
    unsigned short* wp_sl  = wp_mm2 + 16384;
    unsigned short* wp_ul  = wp_sl + 16384;
    int* offs   = (int*)(wp_ul + 16384);
    int* cursor = offs + N_NODES + 1;
    int* perm   = cursor + N_NODES;

    hipMemsetAsync(agg, 0, (size_t)(N_NODES * DD + 2 * N_NODES) * sizeof(float), stream);
    prep_kernel<<<NPACK + NLN + NHIST, 256, 0, stream>>>(
        eg_w1, wm_w1, wm_w2, wm_w3, mm_w1, mm_w2, sl_w, ul_w, wp,
        x, ln_g, ln_b, xn, edst, elen, cnt);
    scan_kernel<<<1, 1024, 0, stream>>>(cnt, offs, cursor);
    fill_kernel<<<N_EDGES / 256, 256, 0, stream>>>(edst, elen, cursor, perm);
    edge_seg_kernel<<<N_EDGES / 256, 256, 0, stream>>>(xn, esrc, edst, rbf, elen,
        perm, offs + N_NODES,
        wp_eg1, wp_w1, wp_w2, wp_w3,
        eg_b1, eg_w2, eg_b2, wm_b1, wm_b2, wm_b3, agg, nrm);
    node_kernel<<<(N_NODES + 127) / 128, 256, 0, stream>>>(x, xn, agg, nrm,
        wp_mm1, wp_mm2, wp_sl, wp_ul,
        mm_b1, mm_b2, sl_b, ul_b, rscl, (float*)d_out);
}